// Round 16
// baseline (642.439 us; speedup 1.0000x reference)
//
#include <hip/hip_runtime.h>
#include <hip/hip_bf16.h>
#include <hip/hip_fp16.h>
#include <math.h>

#define EPS_BN 1e-5f
#define NBK 256

// Wire formats: float inputs bf16 (runtime-detected), ints int32/int64 (detected), OUTPUT FP32.
// r17: conv2 affine decomposition. r18: BN1 moments. r19: z1 tables. r21: weight prepack.
// r23: degS eliminated algebraically. r25: fp16 activations/weights. r26: counting-sort CSR.
// r27: transposed m3 dump + vectorized seg_walk. r28: multi-block head. r30: +XCD swizzle (616).
// r31: 256-thr conv1f/m2stats (2 parallel tile groups) improved conv1f 124->118.6us but the
//      collateral 128-thr pq/lin5m rewrites regressed ~20us (split-N halves per-wave ILP on
//      already-well-shaped 64-thr kernels).
// r32: cherry-pick: keep r31's 256-thr conv1f/m2stats; restore r30's 64-thr pq/lin5m.

typedef float f32x4_t  __attribute__((ext_vector_type(4)));
typedef _Float16 half8_t __attribute__((ext_vector_type(8)));
typedef _Float16 half2_t __attribute__((ext_vector_type(2)));

// ---------- helpers ----------
static __device__ __forceinline__ float bf2f(unsigned short b){
  return __uint_as_float(((unsigned)b) << 16);
}
// fp16 scalar/packed helpers
static __device__ __forceinline__ float h2f(unsigned short u){
  _Float16 h;
  __builtin_memcpy(&h, &u, 2);
  return (float)h;
}
static __device__ __forceinline__ unsigned short f2h(float f){
  _Float16 h = (_Float16)f;
  unsigned short u;
  __builtin_memcpy(&u, &h, 2);
  return u;
}
static __device__ __forceinline__ unsigned pkh2(float a, float b){
  half2_t t = { (_Float16)a, (_Float16)b };
  unsigned u;
  __builtin_memcpy(&u, &t, 4);
  return u;
}
static inline int cdiv(int a, int b){ return (a + b - 1) / b; }
static __device__ __forceinline__ int clampi(int v, int lo, int hi){
  return v < lo ? lo : (v > hi ? hi : v);
}
static __device__ __forceinline__ int ld_idx(const void* p, long e, int m64){
  return m64 ? (int)((const long long*)p)[e] : ((const int*)p)[e];
}
// order-preserving float<->uint
static __device__ __forceinline__ unsigned ordf(float f){
  unsigned b = __float_as_uint(f);
  return (b & 0x80000000u) ? ~b : (b | 0x80000000u);
}
static __device__ __forceinline__ float iordf(unsigned u){
  unsigned b = (u & 0x80000000u) ? (u & 0x7FFFFFFFu) : ~u;
  return __uint_as_float(b);
}
// bijective XCD-aware blockIdx swizzle (m204 form): each XCD gets a contiguous chunk
static __device__ __forceinline__ int xcd_swz(int orig, int nwg){
  int xcd = orig & 7;
  int base = orig >> 3;
  int q = nwg >> 3, r = nwg & 7;
  int start = (xcd < r) ? xcd*(q+1) : r*(q+1) + (xcd - r)*q;
  return start + base;
}

// ---------- sentinel ----------
__global__ void k_sentinel(float* out, int n){
  int i = blockIdx.x*256 + threadIdx.x;
  if (i < n) out[i] = -12288.0f;
}

// ---------- runtime dtype detection ----------
__global__ void k_detect(const void* ei, const void* pos, int* dmode){
  __shared__ int nz, ff;
  if (threadIdx.x == 0){ nz = 0; ff = 0; }
  __syncthreads();
  const int* w32 = (const int*)ei;
  if (w32[1 + 2*threadIdx.x] != 0) nz = 1;
  const unsigned short* ph = (const unsigned short*)pos;
  int bad = 0;
  for (int i = threadIdx.x; i < 8192; i += 256)
    if (((ph[i] >> 7) & 0xFF) == 0xFF) bad = 1;
  if (bad) ff = 1;
  __syncthreads();
  if (threadIdx.x == 0){ dmode[0] = nz ? 0 : 1; dmode[1] = ff; }
}

// ---------- expand float inputs -> fp32 scratch ----------
struct ExpItem { const void* s; float* d; int n; };
struct ExpArgs { ExpItem it[31]; };
__global__ void k_expand(ExpArgs a, int cnt, const int* dmode){
  int i = blockIdx.y;
  if (i >= cnt) return;
  int m32 = dmode[1];
  int t = blockIdx.x*256 + threadIdx.x;
  if (t < a.it[i].n){
    a.it[i].d[t] = m32 ? ((const float*)a.it[i].s)[t]
                       : bf2f(((const unsigned short*)a.it[i].s)[t]);
  }
}

// ---------- fused weight prep: W2/W3/W5 -> fp16, W4 -> P/Q fp16 ----------
__global__ void k_prep(const float* __restrict__ W2, const float* __restrict__ W3,
                       const float* __restrict__ W5, const float* __restrict__ W4,
                       unsigned short* __restrict__ W2h, unsigned short* __restrict__ W3h,
                       unsigned short* __restrict__ W5h,
                       unsigned short* __restrict__ P, unsigned short* __restrict__ Q){
  int i = blockIdx.x*256 + threadIdx.x;
  if (i < 4096) W2h[i] = f2h(W2[i]);
  else if (i < 8192) W3h[i-4096] = f2h(W3[i-4096]);
  else if (i < 24576) W5h[i-8192] = f2h(W5[i-8192]);
  else if (i < 28672){
    int j = i - 24576;
    int c = j >> 6, k = j & 63;
    float b = W4[c*128 + 64 + k];
    P[j] = f2h(W4[c*128 + k] - b);
    Q[j] = f2h(b);
  }
}

// ---------- CSR build: 2-phase counting sort ----------
// phase 0: coarse histogram (256 buckets of KK nodes) via LDS, 256 global atomics/block
__global__ void k_chist(const void* __restrict__ ei, int E, int N, const int* dmode,
                        int KK, int* __restrict__ cbc){
  __shared__ int lh[NBK];
  int tid = threadIdx.x;
  lh[tid] = 0;
  __syncthreads();
  int m64 = dmode[0];
  long base = (long)blockIdx.x*4096;
  for (int k = 0; k < 16; k++){
    long e = base + k*256 + tid;
    if (e < E){
      int nd = clampi(ld_idx(ei, (long)E + e, m64), 0, N-1);
      atomicAdd(&lh[nd/KK], 1);
    }
  }
  __syncthreads();
  if (lh[tid]) atomicAdd(&cbc[tid], lh[tid]);
}

// phase 0b: 256-entry scan -> coarse offsets cof[0..256] + phase-A cursors
__global__ void k_cscan(const int* __restrict__ cbc, int* __restrict__ cof,
                        int* __restrict__ cursorC){
  __shared__ int s[NBK];
  int t = threadIdx.x;
  int d = cbc[t];
  s[t] = d;
  __syncthreads();
  for (int off = 1; off < NBK; off <<= 1){
    int x = (t >= off) ? s[t - off] : 0;
    __syncthreads();
    s[t] += x;
    __syncthreads();
  }
  cof[t + 1] = s[t];
  cursorC[t] = s[t] - d;
  if (t == 0) cof[0] = 0;
}

// phase A: bin edges into coarse buckets. Per-block: LDS count -> reserve contiguous run
// per bucket (1 global atomic) -> stream edges into runs (dense ~128B writes).
// Fused: all 27 BN1 edge moments.
__global__ void k_fillA(const void* __restrict__ ei, int E, int N, const int* dmode,
                        int KK, const float* __restrict__ pos,
                        int* __restrict__ cursorC, int2* __restrict__ tmp,
                        float* __restrict__ mom){
  __shared__ int lh[NBK];
  __shared__ int rb[NBK];
  int tid = threadIdx.x;
  lh[tid] = 0;
  __syncthreads();
  int m64 = dmode[0];
  long base = (long)blockIdx.x*4096;
  for (int k = 0; k < 16; k++){
    long e = base + k*256 + tid;
    if (e < E){
      int nd = clampi(ld_idx(ei, (long)E + e, m64), 0, N-1);
      atomicAdd(&lh[nd/KK], 1);
    }
  }
  __syncthreads();
  int c = lh[tid];
  rb[tid] = c ? atomicAdd(&cursorC[tid], c) : 0;
  lh[tid] = 0;
  __syncthreads();
  float v[27];
  #pragma unroll
  for (int j = 0; j < 27; j++) v[j] = 0.f;
  for (int k = 0; k < 16; k++){
    long e = base + k*256 + tid;
    if (e < E){
      int sv = clampi(ld_idx(ei, e, m64), 0, N-1);
      int nd = clampi(ld_idx(ei, (long)E + e, m64), 0, N-1);
      int b = nd/KK;
      int p = rb[b] + atomicAdd(&lh[b], 1);
      tmp[p] = make_int2(nd, sv);
      float xd0=pos[nd*3+0], xd1=pos[nd*3+1], xd2=pos[nd*3+2];
      float xs0=pos[sv*3+0], xs1=pos[sv*3+1], xs2=pos[sv*3+2];
      v[0]+=xd0; v[1]+=xd1; v[2]+=xd2;
      v[3]+=xs0; v[4]+=xs1; v[5]+=xs2;
      v[6]+=xd0*xd0; v[7]+=xd0*xd1; v[8]+=xd0*xd2; v[9]+=xd1*xd1; v[10]+=xd1*xd2; v[11]+=xd2*xd2;
      v[12]+=xs0*xs0; v[13]+=xs0*xs1; v[14]+=xs0*xs2; v[15]+=xs1*xs1; v[16]+=xs1*xs2; v[17]+=xs2*xs2;
      v[18]+=xd0*xs0; v[19]+=xd0*xs1; v[20]+=xd0*xs2;
      v[21]+=xd1*xs0; v[22]+=xd1*xs1; v[23]+=xd1*xs2;
      v[24]+=xd2*xs0; v[25]+=xd2*xs1; v[26]+=xd2*xs2;
    }
  }
  #pragma unroll
  for (int m = 1; m < 64; m <<= 1){
    #pragma unroll
    for (int j = 0; j < 27; j++) v[j] += __shfl_xor(v[j], m, 64);
  }
  int lane = tid & 63;
  int wflat = (blockIdx.x*256 + tid) >> 6;
  if (lane == 0){
    float* mr = &mom[(size_t)(wflat & 63)*32];
    #pragma unroll
    for (int j = 0; j < 27; j++) atomicAdd(&mr[j], v[j]);
  }
}

// phase B: one block per coarse bucket. Local hist -> deg (dense), scan -> offs (dense),
// redistribute bucket edges to exact CSR positions (block-owned range, low write-amp).
__global__ void __launch_bounds__(512, 1)
k_fillB(const int2* __restrict__ tmp, const int* __restrict__ cof, int N, int E, int KK,
        int* __restrict__ deg, int* __restrict__ offs, int2* __restrict__ es){
  __shared__ int lh[512];
  __shared__ int lc[512];
  int tid = threadIdx.x, b = blockIdx.x;
  int nd0 = b*KK;
  int nd1 = nd0 + KK; if (nd1 > N) nd1 = N;
  int nn = nd1 - nd0; if (nn < 0) nn = 0;
  int gbase = cof[b], gend = cof[b+1];
  int cnt = gend - gbase;
  lh[tid] = 0;
  __syncthreads();
  for (int t = tid; t < cnt; t += 512)
    atomicAdd(&lh[tmp[gbase + t].x - nd0], 1);
  __syncthreads();
  int d = lh[tid];
  for (int off = 1; off < 512; off <<= 1){
    int x = (tid >= off) ? lh[tid - off] : 0;
    __syncthreads();
    lh[tid] += x;
    __syncthreads();
  }
  int excl = lh[tid] - d;
  if (tid < nn){
    deg[nd0 + tid] = d;
    offs[nd0 + tid] = gbase + excl;
  }
  lc[tid] = excl;
  if (b == gridDim.x - 1 && tid == 0) offs[N] = E;
  __syncthreads();
  for (int t = tid; t < cnt; t += 512){
    int2 e2 = tmp[gbase + t];
    int lpos = atomicAdd(&lc[e2.x - nd0], 1);
    es[gbase + lpos] = e2;
  }
}

// ---------- BN1 finalize from moments ----------
__global__ void k_bn1(const float* __restrict__ mom, float Ef,
                      const float* __restrict__ W1, const float* __restrict__ b1,
                      const float* __restrict__ g, const float* __restrict__ be,
                      float* __restrict__ ss){
  __shared__ float sm[27];
  int t = threadIdx.x;
  if (t < 27){
    float s = 0.f;
    for (int r = 0; r < 64; r++) s += mom[(size_t)r*32 + t];
    sm[t] = s;
  }
  __syncthreads();
  if (t < 64){
    float P0 = W1[t*6+0]-W1[t*6+3], P1 = W1[t*6+1]-W1[t*6+4], P2 = W1[t*6+2]-W1[t*6+5];
    float Q0 = W1[t*6+3], Q1 = W1[t*6+4], Q2 = W1[t*6+5];
    float b = b1[t];
    float vD0=sm[0],vD1=sm[1],vD2=sm[2], vS0=sm[3],vS1=sm[4],vS2=sm[5];
    float PvD = P0*vD0 + P1*vD1 + P2*vD2;
    float QvS = Q0*vS0 + Q1*vS1 + Q2*vS2;
    float sum = PvD + QvS + Ef*b;
    float PMDP = P0*(sm[6]*P0 + sm[7]*P1 + sm[8]*P2)
               + P1*(sm[7]*P0 + sm[9]*P1 + sm[10]*P2)
               + P2*(sm[8]*P0 + sm[10]*P1 + sm[11]*P2);
    float QMSQ = Q0*(sm[12]*Q0 + sm[13]*Q1 + sm[14]*Q2)
               + Q1*(sm[13]*Q0 + sm[15]*Q1 + sm[16]*Q2)
               + Q2*(sm[14]*Q0 + sm[16]*Q1 + sm[17]*Q2);
    float PGQ = P0*(sm[18]*Q0 + sm[19]*Q1 + sm[20]*Q2)
              + P1*(sm[21]*Q0 + sm[22]*Q1 + sm[23]*Q2)
              + P2*(sm[24]*Q0 + sm[25]*Q1 + sm[26]*Q2);
    float sumsq = PMDP + 2.f*b*PvD + Ef*b*b + QMSQ + 2.f*(PGQ + b*QvS);
    float mean = sum / Ef;
    float var  = fmaxf(sumsq / Ef - mean*mean, 0.f);
    float inv  = rsqrtf(var + EPS_BN);
    float sc   = g[t] * inv;
    ss[t]      = sc;
    ss[64 + t] = be[t] - mean*sc;
  }
}

// ---------- z1 tables (fp16): a' = sc1.(P.x+b1)+sh1, b = sc1.(Q.x) ----------
__global__ void k_ab(const float* __restrict__ pos, int N,
                     const float* __restrict__ W1, const float* __restrict__ b1,
                     const float* __restrict__ ss1,
                     unsigned short* __restrict__ at, unsigned short* __restrict__ bt){
  int n = blockIdx.x*256 + threadIdx.x;
  if (n >= N) return;
  float x0 = pos[n*3+0], x1 = pos[n*3+1], x2 = pos[n*3+2];
  unsigned short* ar = at + (size_t)n*64;
  unsigned short* br = bt + (size_t)n*64;
  #pragma unroll
  for (int c2 = 0; c2 < 64; c2 += 2){
    float av[2], bv[2];
    #pragma unroll
    for (int u = 0; u < 2; u++){
      int c = c2 + u;
      float q0 = W1[c*6+3], q1 = W1[c*6+4], q2 = W1[c*6+5];
      float p0 = W1[c*6+0]-q0, p1 = W1[c*6+1]-q1, p2 = W1[c*6+2]-q2;
      float sc = ss1[c], sh = ss1[64+c];
      float pa = fmaf(p0,x0, fmaf(p1,x1, fmaf(p2,x2, b1[c])));
      float qb = fmaf(q0,x0, fmaf(q1,x1, q2*x2));
      av[u] = fmaf(pa, sc, sh);
      bv[u] = qb * sc;
    }
    *(unsigned*)&ar[c2] = pkh2(av[0], av[1]);
    *(unsigned*)&br[c2] = pkh2(bv[0], bv[1]);
  }
}

// ---------- finalize BN (generic, from repl) ----------
__global__ void k_finalize(float* __restrict__ repl, int C, float count,
                           const float* __restrict__ g, const float* __restrict__ be,
                           float* __restrict__ ss){
  int c = threadIdx.x;
  if (c < C){
    float s = 0.f, q = 0.f;
    for (int r = 0; r < 64; r++){
      s += repl[r*256 + c];       repl[r*256 + c] = 0.f;
      q += repl[r*256 + 128 + c]; repl[r*256 + 128 + c] = 0.f;
    }
    float mean = s / count;
    float var  = fmaxf(q / count - mean*mean, 0.f);
    float inv  = rsqrtf(var + EPS_BN);
    float sc   = g[c] * inv;
    ss[c]     = sc;
    ss[C + c] = be[c] - mean*sc;
  }
}

// ---------- MFMA building blocks (fp16, NT-generic) ----------
// A layout (m120): lane holds A[m=lane&15][k=(lane>>4)*8+j]
// C/D layout (m89/m91, dtype-independent): col=lane&15, row=(lane>>4)*4+reg
template<int NT, int KT>
static __device__ __forceinline__ void loadBh2(const unsigned short* __restrict__ Wp, int c15, int q,
                                               half8_t bf[NT][KT]){
  #pragma unroll
  for (int nt = 0; nt < NT; nt++){
    int c = nt*16 + c15;
    #pragma unroll
    for (int kt = 0; kt < KT; kt++)
      bf[nt][kt] = *(const half8_t*)(Wp + (size_t)c*(KT*32) + kt*32 + q*8);
  }
}
template<int NT, int KT, int ST>
static __device__ __forceinline__ void do_mfma2(const unsigned short* Aw, half8_t bf[NT][KT],
                                                const float* __restrict__ bias, int c15, int q,
                                                f32x4_t acc[4][NT]){
  #pragma unroll
  for (int mt = 0; mt < 4; mt++)
    #pragma unroll
    for (int nt = 0; nt < NT; nt++){
      float bv = bias[nt*16 + c15];
      acc[mt][nt] = (f32x4_t){bv, bv, bv, bv};
    }
  #pragma unroll
  for (int mt = 0; mt < 4; mt++){
    #pragma unroll
    for (int kt = 0; kt < KT; kt++){
      half8_t af = *(const half8_t*)&Aw[(mt*16 + c15)*ST + kt*32 + q*8];
      #pragma unroll
      for (int nt = 0; nt < NT; nt++)
        acc[mt][nt] = __builtin_amdgcn_mfma_f32_16x16x32_f16(af, bf[nt][kt], acc[mt][nt], 0, 0, 0);
    }
  }
}
template<int NT>
static __device__ __forceinline__ void stats_acc2(f32x4_t acc[4][NT], long tb, int E,
                                                  int lane, int q, int r_idx, int choff,
                                                  float* __restrict__ repl){
  #pragma unroll
  for (int nt = 0; nt < NT; nt++){
    float s = 0.f, qq = 0.f;
    #pragma unroll
    for (int mt = 0; mt < 4; mt++){
      #pragma unroll
      for (int r = 0; r < 4; r++){
        long eidx = tb + mt*16 + q*4 + r;
        float v = (eidx < E) ? acc[mt][nt][r] : 0.f;
        s += v; qq += v*v;
      }
    }
    s += __shfl_xor(s, 16, 64); qq += __shfl_xor(qq, 16, 64);
    s += __shfl_xor(s, 32, 64); qq += __shfl_xor(qq, 32, 64);
    if (lane < 16){
      atomicAdd(&repl[r_idx*256 + choff + nt*16 + lane], s);
      atomicAdd(&repl[r_idx*256 + 128 + choff + nt*16 + lane], qq);
    }
  }
}
template<int NT, int ST>
static __device__ __forceinline__ void dumpC2(f32x4_t acc[4][NT], unsigned short* Cw,
                                              int colbase, int c15, int q){
  #pragma unroll
  for (int mt = 0; mt < 4; mt++)
    #pragma unroll
    for (int nt = 0; nt < NT; nt++){
      int col = colbase + nt*16 + c15;
      #pragma unroll
      for (int r = 0; r < 4; r += 2){
        unsigned p = pkh2(acc[mt][nt][r], acc[mt][nt][r+1]);
        int row = mt*16 + q*4 + r;
        Cw[row*ST + col]        = (unsigned short)p;
        Cw[(row + 1)*ST + col]  = (unsigned short)(p >> 16);
      }
    }
}
// transposed dump for m3: CT[ch][edge], stride 68 ushort (136 B). Row-pairs -> one u32.
static __device__ __forceinline__ void dumpC2T(f32x4_t acc[4][2], unsigned short* CT,
                                               int colbase, int c15, int q){
  #pragma unroll
  for (int mt = 0; mt < 4; mt++)
    #pragma unroll
    for (int nt = 0; nt < 2; nt++){
      int col = colbase + nt*16 + c15;
      #pragma unroll
      for (int r = 0; r < 4; r += 2){
        unsigned p = pkh2(acc[mt][nt][r], acc[mt][nt][r+1]);
        int row = mt*16 + q*4 + r;
        *(unsigned*)((char*)CT + col*136 + row*2) = p;
      }
    }
}
// segmented raw min/max over transposed tile; t2 in [0,128): ch = t2&63, k-half = t2>>6.
// Vectorized: 8x ds_read_b64 values (contiguous per channel) + 8x broadcast int4 nds.
static __device__ __forceinline__ void seg_walk3(const unsigned short* CT, const int* nds,
                                                 long tb, int E, int t2,
                                                 unsigned* __restrict__ tmax,
                                                 unsigned* __restrict__ tmin){
  int lane = t2 & 63, par = t2 >> 6;
  long rem = (long)E - tb;
  int limit = rem >= 64 ? 64 : (rem > 0 ? (int)rem : 0);
  int k0 = par*32;
  int cnt = limit - k0; if (cnt > 32) cnt = 32;
  if (cnt <= 0) return;
  const char* base = (const char*)CT + lane*136 + k0*2;
  uint2 dv[8];
  #pragma unroll
  for (int j = 0; j < 8; j++) dv[j] = *(const uint2*)(base + j*8);
  int nd[32];
  #pragma unroll
  for (int j = 0; j < 8; j++) *(int4*)&nd[j*4] = *(const int4*)&nds[k0 + j*4];
  int cur = nd[0];
  float mx = -3.4e38f, mn = 3.4e38f;
  #pragma unroll
  for (int k = 0; k < 32; k++){
    unsigned w = (k & 2) ? dv[k>>2].y : dv[k>>2].x;
    unsigned short hv = (k & 1) ? (unsigned short)(w >> 16) : (unsigned short)(w & 0xffffu);
    float v = h2f(hv);
    bool act = (k < cnt);
    int ndk = act ? nd[k] : cur;
    if (ndk != cur){
      atomicMax(&tmax[(size_t)cur*64 + lane], ordf(mx));
      atomicMin(&tmin[(size_t)cur*64 + lane], ordf(mn));
      cur = ndk; mx = v; mn = v;
    } else if (act){
      mx = fmaxf(mx, v); mn = fminf(mn, v);
    }
  }
  atomicMax(&tmax[(size_t)cur*64 + lane], ordf(mx));
  atomicMin(&tmin[(size_t)cur*64 + lane], ordf(mn));
}
// packed fp16 add + relu (v_pk_add_f16 + v_pk_max_f16) via native _Float16 vectors
static __device__ __forceinline__ unsigned rladd2h(unsigned a, unsigned b){
  half2_t ha, hb;
  __builtin_memcpy(&ha, &a, 4);
  __builtin_memcpy(&hb, &b, 4);
  half2_t s = ha + hb;
  half2_t z = { (_Float16)0, (_Float16)0 };
  half2_t r = __builtin_elementwise_max(s, z);
  unsigned u;
  __builtin_memcpy(&u, &r, 4);
  return u;
}
// stage half (32 channels) of z1 = relu(a'[dst] + b[src]) into A row
static __device__ __forceinline__ void stage_z1t_half(const unsigned short* __restrict__ at,
                                                      const unsigned short* __restrict__ bt,
                                                      int di, int si, int h, unsigned short* Ar){
  const uint4* a4 = (const uint4*)(at + (size_t)di*64 + h*32);
  const uint4* b4 = (const uint4*)(bt + (size_t)si*64 + h*32);
  #pragma unroll
  for (int k = 0; k < 4; k++){
    uint4 av = a4[k], bv = b4[k], o;
    o.x = rladd2h(av.x, bv.x); o.y = rladd2h(av.y, bv.y);
    o.z = rladd2h(av.z, bv.z); o.w = rladd2h(av.w, bv.w);
    *(uint4*)&Ar[k*8] = o;
  }
}

// ---------- m2 stats only (CSR order, 2 parallel 2-wave tile groups, XCD-swizzled) ----------
__global__ void __launch_bounds__(256, 1)
k_m2stats(const int2* __restrict__ es,
          const unsigned short* __restrict__ at, const unsigned short* __restrict__ bt,
          int E,
          const unsigned short* __restrict__ W2h, const float* __restrict__ b2,
          float* __restrict__ repl){
  __shared__ unsigned short A[2][64][72];
  int tid = threadIdx.x;
  int g = tid >> 7, t2 = tid & 127;
  int lane = t2 & 63, wv = t2 >> 6;
  int swz = xcd_swz(blockIdx.x, gridDim.x);
  long tb = (long)(swz*2 + g)*64;
  long e = tb + lane;
  unsigned short* Ar = &A[g][lane][wv*32];
  if (e < E){
    int2 e2 = es[e];
    stage_z1t_half(at, bt, e2.x, e2.y, wv, Ar);
  } else {
    #pragma unroll
    for (int k = 0; k < 4; k++) *(uint4*)&Ar[k*8] = make_uint4(0u,0u,0u,0u);
  }
  __syncthreads();
  int c15 = lane & 15, q = lane >> 4;
  half8_t bf[2][2];
  loadBh2<2,2>(W2h + (size_t)(wv*32)*64, c15, q, bf);
  f32x4_t acc[4][2];
  do_mfma2<2,2,72>(&A[g][0][0], bf, b2 + wv*32, c15, q, acc);
  stats_acc2<2>(acc, tb, E, lane, q, (swz*2 + g) & 63, wv*32, repl);
}

// ---------- conv1 fused (2 parallel 2-wave tile groups, XCD-swizzled) ----------
__global__ void __launch_bounds__(256, 1)
k_conv1f(const unsigned short* __restrict__ at, const unsigned short* __restrict__ bt,
         const int2* __restrict__ es, int E,
         const float* __restrict__ ss2,
         const unsigned short* __restrict__ W2h, const float* __restrict__ b2,
         const unsigned short* __restrict__ W3h, const float* __restrict__ b3,
         float* __restrict__ repl, unsigned* __restrict__ tmax, unsigned* __restrict__ tmin){
  __shared__ unsigned short A[2][64][72];
  __shared__ int nds[2][64];
  int tid = threadIdx.x;
  int g = tid >> 7, t2 = tid & 127;
  int lane = t2 & 63, wv = t2 >> 6;
  int swz = xcd_swz(blockIdx.x, gridDim.x);
  long tb = (long)(swz*2 + g)*64;
  long t = tb + lane;
  unsigned short* Ar = &A[g][lane][wv*32];
  if (t < E){
    int2 e2 = es[t];
    if (wv == 0) nds[g][lane] = e2.x;
    stage_z1t_half(at, bt, e2.x, e2.y, wv, Ar);
  } else {
    if (wv == 0) nds[g][lane] = 0;
    #pragma unroll
    for (int k = 0; k < 4; k++) *(uint4*)&Ar[k*8] = make_uint4(0u,0u,0u,0u);
  }
  __syncthreads();
  int c15 = lane & 15, q = lane >> 4;
  unsigned short* Aw = &A[g][0][0];
  f32x4_t acc[4][2];
  {
    half8_t bf[2][2];
    loadBh2<2,2>(W2h + (size_t)(wv*32)*64, c15, q, bf);
    do_mfma2<2,2,72>(Aw, bf, b2 + wv*32, c15, q, acc);
  }
  #pragma unroll
  for (int nt = 0; nt < 2; nt++){
    int ch = wv*32 + nt*16 + c15;
    float sc = ss2[ch], sh = ss2[64 + ch];
    #pragma unroll
    for (int mt = 0; mt < 4; mt++)
      #pragma unroll
      for (int r = 0; r < 4; r++)
        acc[mt][nt][r] = fmaxf(fmaf(acc[mt][nt][r], sc, sh), 0.f);
  }
  __syncthreads();
  dumpC2<2,72>(acc, Aw, wv*32, c15, q);
  __syncthreads();
  {
    half8_t bf[2][2];
    loadBh2<2,2>(W3h + (size_t)(wv*32)*64, c15, q, bf);
    do_mfma2<2,2,72>(Aw, bf, b3 + wv*32, c15, q, acc);
  }
  stats_acc2<2>(acc, tb, E, lane, q, (swz*2 + g) & 63, wv*32, repl);
  __syncthreads();
  // m3 C transposed into the (now dead) A buffer: CT[ch][edge], stride 68
  dumpC2T(acc, Aw, wv*32, c15, q);
  __syncthreads();
  seg_walk3(Aw, nds[g], tb, E, t2, tmax, tmin);
}

// ---------- conv2 decomposed (r30 64-thr): per-node p = P@x+b4, q = Q@x ----------
__global__ void __launch_bounds__(64, 1)
k_pq(const unsigned short* __restrict__ x1, int N,
     const unsigned short* __restrict__ Pmh, const unsigned short* __restrict__ Qmh,
     const float* __restrict__ b4, const float* __restrict__ zeros64,
     unsigned short* __restrict__ up, unsigned short* __restrict__ uq){
  __shared__ unsigned short A[64][72];
  __shared__ unsigned short Cb[64][72];
  int lane = threadIdx.x;
  long nb0 = (long)blockIdx.x*64;
  long n = nb0 + lane;
  unsigned short* Ar = &A[lane][0];
  if (n < N){
    const uint4* a4 = (const uint4*)(x1 + (size_t)n*64);
    #pragma unroll
    for (int k = 0; k < 8; k++) *(uint4*)&Ar[k*8] = a4[k];
  } else {
    #pragma unroll
    for (int k = 0; k < 8; k++) *(uint4*)&Ar[k*8] = make_uint4(0u,0u,0u,0u);
  }
  __syncthreads();
  int c15 = lane & 15, q = lane >> 4;
  unsigned short* Aw = &A[0][0];
  unsigned short* Cw = &Cb[0][0];
  for (int h = 0; h < 2; h++){
    const unsigned short* Wp = h ? Qmh : Pmh;
    const float* bp = h ? zeros64 : b4;
    unsigned short* out = h ? uq : up;
    half8_t bf[4][2];
    loadBh2<4,2>(Wp, c15, q, bf);
    f32x4_t acc[4][4];
    do_mfma2<4,2,72>(Aw, bf, bp, c15, q, acc);
    dumpC2<4,72>(acc, Cw, 0, c15, q);
    __syncthreads();
    int rl = lane >> 3, ch8 = lane & 7;
    #pragma unroll
    for (int pass = 0; pass < 8; pass++){
      int row = pass*8 + rl;
      long nn = nb0 + row;
      if (nn < N)
        *(uint4*)(out + (size_t)nn*64 + ch8*8) = *(const uint4*)&Cw[row*72 + ch8*8];
    }
    __syncthreads();
  }
}

// ---------- conv2 edge pass: gather max/min of q + FULL BN4 stats from segments ----------
#define NPW 8
__global__ void k_edge2(const int* __restrict__ offs, const int2* __restrict__ es,
                        const unsigned short* __restrict__ uq, const unsigned short* __restrict__ up,
                        int N, float* __restrict__ tmaxF, float* __restrict__ tminF,
                        float* __restrict__ repl){
  int wv = threadIdx.x >> 6, lane = threadIdx.x & 63;
  int w_id = blockIdx.x*4 + wv;
  int n0 = w_id * NPW;
  int nend = n0 + NPW; if (nend > N) nend = N;
  float s_acc = 0.f, ss_acc = 0.f;
  for (int n = n0; n < nend; n++){
    int e0 = offs[n], e1 = offs[n+1];
    if (e1 <= e0) continue;
    float mx = -3.4e38f, mn = 3.4e38f, qs = 0.f, qsq = 0.f;
    int t = e0;
    for (; t + 4 <= e1; t += 4){
      int s0 = es[t].y, s1 = es[t+1].y, s2 = es[t+2].y, s3 = es[t+3].y;
      float v0 = h2f(uq[(size_t)s0*64 + lane]);
      float v1 = h2f(uq[(size_t)s1*64 + lane]);
      float v2 = h2f(uq[(size_t)s2*64 + lane]);
      float v3 = h2f(uq[(size_t)s3*64 + lane]);
      mx = fmaxf(mx, fmaxf(fmaxf(v0, v1), fmaxf(v2, v3)));
      mn = fminf(mn, fminf(fminf(v0, v1), fminf(v2, v3)));
      qs += (v0 + v1) + (v2 + v3);
      qsq += v0*v0 + v1*v1 + v2*v2 + v3*v3;
    }
    for (; t < e1; t++){
      int s0 = es[t].y;
      float v0 = h2f(uq[(size_t)s0*64 + lane]);
      mx = fmaxf(mx, v0); mn = fminf(mn, v0); qs += v0; qsq += v0*v0;
    }
    float pv = h2f(up[(size_t)n*64 + lane]);
    float deg = (float)(e1 - e0);
    // Sum_e (p+q) = deg*p + qs ; Sum_e (p+q)^2 = deg*p^2 + 2p*qs + qsq
    s_acc  += fmaf(deg, pv, qs);
    ss_acc += fmaf(deg*pv, pv, fmaf(2.f*pv, qs, qsq));
    tmaxF[(size_t)n*64 + lane] = mx;
    tminF[(size_t)n*64 + lane] = mn;
  }
  int r_idx = w_id & 63;
  atomicAdd(&repl[r_idx*256 + lane], s_acc);
  atomicAdd(&repl[r_idx*256 + 128 + lane], ss_acc);
}

// ---------- conv2 post: x2 = relu(sc*(p + qext) + sh), 0 for empty segments ----------
__global__ void k_applybn2(unsigned short* __restrict__ x2 /* in: up, out: x2 (in-place) */,
                           const float* __restrict__ tmaxF, const float* __restrict__ tminF,
                           const int* __restrict__ degD, const float* __restrict__ ss,
                           long total){
  long i = (long)blockIdx.x*256 + threadIdx.x;
  if (i >= total) return;
  int c = (int)(i & 63);
  long n = i >> 6;
  float out = 0.f;
  if (degD[n] > 0){
    float sc = ss[c], sh = ss[64 + c];
    float v = h2f(x2[i]) + ((sc >= 0.f) ? tmaxF[i] : tminF[i]);
    out = fmaxf(fmaf(v, sc, sh), 0.f);
  }
  x2[i] = f2h(out);
}

// ---------- apply BN post-aggregation (conv1) ----------
__global__ void k_applybn(const unsigned* __restrict__ tmax, const unsigned* __restrict__ tmin,
                          const float* __restrict__ ss, long total,
                          unsigned short* __restrict__ xout){
  long i = (long)blockIdx.x*256 + threadIdx.x;
  if (i >= total) return;
  int c = (int)(i & 63);
  unsigned um = tmax[i];
  float out = 0.f;
  if (um != 0u){
    float sc = ss[c], sh = ss[64 + c];
    float v = (sc >= 0.f) ? iordf(um) : iordf(tmin[i]);
    out = fmaxf(fmaf(v, sc, sh), 0.f);
  }
  xout[i] = f2h(out);
}

// ---------- lin5 (r30 64-thr): y5 = cat(x1,x2)@W5^T + b5, fused BN5 stats ----------
__global__ void __launch_bounds__(64, 1)
k_lin5m(const unsigned short* __restrict__ x1, const unsigned short* __restrict__ x2,
        int N, const unsigned short* __restrict__ W5h, const float* __restrict__ b5,
        unsigned short* __restrict__ y5, float* __restrict__ repl){
  __shared__ unsigned short A[64][136];
  __shared__ unsigned short Cb[64][72];
  int lane = threadIdx.x;
  long nb0 = (long)blockIdx.x*64;
  long n = nb0 + lane;
  unsigned short* Ar = &A[lane][0];
  if (n < N){
    const uint4* a4 = (const uint4*)(x1 + (size_t)n*64);
    const uint4* b4 = (const uint4*)(x2 + (size_t)n*64);
    #pragma unroll
    for (int k = 0; k < 8; k++) *(uint4*)&Ar[k*8]      = a4[k];
    #pragma unroll
    for (int k = 0; k < 8; k++) *(uint4*)&Ar[64 + k*8] = b4[k];
  } else {
    #pragma unroll
    for (int k = 0; k < 16; k++) *(uint4*)&Ar[k*8] = make_uint4(0u,0u,0u,0u);
  }
  __syncthreads();
  int c15 = lane & 15, q = lane >> 4;
  int r_idx = blockIdx.x & 63;
  unsigned short* Aw = &A[0][0];
  unsigned short* Cw = &Cb[0][0];
  for (int h = 0; h < 2; h++){
    const unsigned short* Wp = W5h + (size_t)h*64*128;
    half8_t bf[4][4];
    loadBh2<4,4>(Wp, c15, q, bf);
    f32x4_t acc[4][4];
    do_mfma2<4,4,136>(Aw, bf, b5 + h*64, c15, q, acc);
    stats_acc2<4>(acc, nb0, N, lane, q, r_idx, h*64, repl);
    dumpC2<4,72>(acc, Cw, 0, c15, q);
    __syncthreads();
    int rl = lane >> 3, ch8 = lane & 7;
    #pragma unroll
    for (int pass = 0; pass < 8; pass++){
      int row = pass*8 + rl;
      long nn = nb0 + row;
      if (nn < N)
        *(uint4*)(y5 + (size_t)nn*128 + h*64 + ch8*8) = *(const uint4*)&Cw[row*72 + ch8*8];
    }
    __syncthreads();
  }
}

// ---------- pool ----------
__global__ void k_pool(const unsigned short* __restrict__ y5, const void* __restrict__ batch, int N,
                       const int* dmode, const float* __restrict__ ss5, unsigned int* __restrict__ pooled){
  int m64 = dmode[0];
  int c = threadIdx.x & 127;
  int par = threadIdx.x >> 7;
  int n0 = blockIdx.x*128;
  int n1 = min(n0 + 128, N);
  float sc = ss5[c], sh = ss5[128 + c];
  int curb = -1; float curm = 0.f;
  for (int n = n0 + par; n < n1; n += 2){
    int b = clampi(ld_idx(batch, (long)n, m64), 0, 63);
    float v = fmaf(h2f(y5[(size_t)n*128 + c]), sc, sh);
    if (b != curb){
      if (curb >= 0) atomicMax(&pooled[curb*128 + c], __float_as_uint(fmaxf(curm, 0.f)));
      curb = b; curm = v;
    } else {
      curm = fmaxf(curm, v);
    }
  }
  if (curb >= 0) atomicMax(&pooled[curb*128 + c], __float_as_uint(fmaxf(curm, 0.f)));
}

// ---------- head (multi-block, unfused) ----------
// lin6: Y = pooled(float bits) @ W6^T + b6
__global__ void k_linH6(const unsigned int* __restrict__ X, const float* __restrict__ W,
                        const float* __restrict__ b, float* __restrict__ Y){
  int cell = blockIdx.x*256 + threadIdx.x;
  if (cell >= 8192) return;
  int r = cell >> 7, c = cell & 127;
  const unsigned int* xr = X + r*128;
  const float* wr = W + c*128;
  float a = b[c];
  for (int j = 0; j < 128; j++) a = fmaf(__uint_as_float(xr[j]), wr[j], a);
  Y[cell] = a;
}

// BN stats over 64 rows -> ss
__global__ void k_bnH(const float* __restrict__ Y, int CO,
                      const float* __restrict__ g, const float* __restrict__ be,
                      float* __restrict__ ss){
  int c = threadIdx.x;
  if (c >= CO) return;
  float s = 0.f;
  for (int r = 0; r < 64; r++) s += Y[r*CO + c];
  float mean = s * (1.f/64.f);
  float q = 0.f;
  for (int r = 0; r < 64; r++){ float d = Y[r*CO + c] - mean; q += d*d; }
  float var = fmaxf(q * (1.f/64.f), 0.f);
  float inv = rsqrtf(var + EPS_BN);
  float sc = g[c] * inv;
  ss[c] = sc;
  ss[CO + c] = be[c] - mean*sc;
}

// lin with BN+relu folded on the input: Z[r][c] = b[c] + sum_j relu(Y[r][j]*sc[j]+sh[j])*W[c][j]
__global__ void k_linHR(const float* __restrict__ Y, const float* __restrict__ ssH,
                        const float* __restrict__ W, const float* __restrict__ b,
                        int CO, float* __restrict__ Z){
  int cell = blockIdx.x*256 + threadIdx.x;
  if (cell >= 64*CO) return;
  int r = cell / CO, c = cell - r*CO;
  const float* xr = Y + r*128;
  const float* wr = W + c*128;
  float a = b[c];
  for (int j = 0; j < 128; j++){
    float x = fmaxf(fmaf(xr[j], ssH[j], ssH[128 + j]), 0.f);
    a = fmaf(x, wr[j], a);
  }
  Z[cell] = a;
}

__global__ void k_logsm(const float* __restrict__ Z, float* __restrict__ out){
  int r = threadIdx.x;   // 64 threads
  const float* zr = Z + r*40;
  float m = zr[0];
  for (int c = 1; c < 40; c++) m = fmaxf(m, zr[c]);
  float s = 0.f;
  for (int c = 0; c < 40; c++) s += expf(zr[c] - m);
  float ls = logf(s);
  for (int c = 0; c < 40; c++) out[r*40 + c] = zr[c] - m - ls;
}

// ---------- launch ----------
extern "C" void kernel_launch(void* const* d_in, const int* in_sizes, int n_in,
                              void* d_out, int out_size, void* d_ws, size_t ws_size,
                              hipStream_t stream) {
  const void* pos   = d_in[0];
  const void* ei    = d_in[1];
  const void* batch = d_in[2];
  (void)n_in;

  const int N = in_sizes[0] / 3;
  const int E = in_sizes[1] / 2;
  const int KK = cdiv(N, NBK);   // nodes per coarse bucket

  // ---- workspace layout ----
  auto al = [](size_t x){ return (x + 255) & ~(size_t)255; };
  char* w = (char*)d_ws;
  size_t o = 0;
  float* repl = (float*)(w + o);                 o += (size_t)64*256*4;
  unsigned int* pooled = (unsigned int*)(w + o); o += (size_t)64*128*4;
  float* zeros64 = (float*)(w + o);              o += 256;
  float* mom = (float*)(w + o);                  o += (size_t)64*32*4;
  int* cbc = (int*)(w + o);                      o += 1024;
  size_t zero_bytes = o;
  int* cof = (int*)(w + o);                      o += 2048;
  int* cursorC = (int*)(w + o);                  o += 1024;
  int* deg = (int*)(w + o);                      o += al((size_t)4*N);
  unsigned* tmaxA = (unsigned*)(w + o);          o += (size_t)64*N*4;
  unsigned* tminA = (unsigned*)(w + o);          o += (size_t)64*N*4;
  // conv2 float min/max reuse conv1's buffers (consumed by k_applybn before k_edge2)
  float* tmaxF = (float*)tmaxA;
  float* tminF = (float*)tminA;
  int* dmode = (int*)(w + o);                    o += 256;
  int* offs = (int*)(w + o);                     o += al((size_t)4*(N + 1));
  int2* tmp = (int2*)(w + o);                    o += al((size_t)8*E);
  int2* es = (int2*)(w + o);                     o += al((size_t)8*E);
  float* ss1 = (float*)(w + o);                  o += 1024;
  float* ss2 = (float*)(w + o);                  o += 1024;
  float* ss3 = (float*)(w + o);                  o += 1024;
  float* ss4 = (float*)(w + o);                  o += 1024;
  float* ss5 = (float*)(w + o);                  o += 1024;
  float* ssH = (float*)(w + o);                  o += 1024;
  float* Y6 = (float*)(w + o);                   o += (size_t)8192*4;
  float* Y7 = (float*)(w + o);                   o += (size_t)8192*4;
  float* Zl = (float*)(w + o);                   o += al((size_t)2560*4);
  unsigned short* W2h = (unsigned short*)(w + o); o += 8192;
  unsigned short* W3h = (unsigned short*)(w + o); o += 8192;
  unsigned short* W5h = (unsigned short*)(w + o); o += 32768;
  unsigned short* Pmh = (unsigned short*)(w + o); o += 8192;
  unsigned short* Qmh = (unsigned short*)(w + o); o += 8192;
  // fp32 expansion region
  float* expBase = (float*)(w + o);
  float* ep = expBase;
  float* epos = ep; ep += (size_t)3*N;
  float* eW[9], *eb[9], *eg[9], *ebe[9];
  const int wsz[9] = {0, 64*6, 64*64, 64*64, 64*128, 128*128, 128*128, 128*128, 40*128};
  const int bsz[9] = {0, 64, 64, 64, 64, 128, 128, 128, 40};
  for (int i = 1; i <= 8; i++){
    eW[i] = ep; ep += wsz[i];
    eb[i] = ep; ep += bsz[i];
    if (i < 8){ eg[i] = ep; ep += bsz[i]; ebe[i] = ep; ep += bsz[i]; }
  }
  long expCount = (long)(ep - expBase);
  o += al((size_t)expCount * 4);
  unsigned short* x1b = (unsigned short*)(w + o); o += al((size_t)2*64*N);
  unsigned short* x2b = (unsigned short*)(w + o); o += al((size_t)2*64*N);  // also holds p (up)
  unsigned short* uqb = (unsigned short*)(w + o); o += al((size_t)2*64*N);
  unsigned short* atb = (unsigned short*)(w + o); o += al((size_t)2*64*N);  // z1 table a'
  unsigned short* btb = (unsigned short*)(w + o); o += al((size_t)2*64*N);  // z1 table b
  unsigned short* y5b = (unsigned short*)(w + o); o += al((size_t)2*128*N);

  float* out_f = (float*)d_out;
  if (ws_size < o){
    k_sentinel<<<cdiv(out_size,256), 256, 0, stream>>>(out_f, out_size);
    return;
  }

  hipMemsetAsync(w, 0, zero_bytes, stream);
  hipMemsetAsync(tmaxA, 0x00, (size_t)64*N*4, stream);
  hipMemsetAsync(tminA, 0xFF, (size_t)64*N*4, stream);
  k_detect<<<1, 256, 0, stream>>>(ei, pos, dmode);

  // expand all float inputs -> fp32
  ExpArgs ea;
  int it = 0;
  ea.it[it++] = {pos, epos, 3*N};
  int di_idx = 3;
  for (int i = 1; i <= 8; i++){
    ea.it[it++] = {d_in[di_idx++], eW[i], wsz[i]};
    ea.it[it++] = {d_in[di_idx++], eb[i], bsz[i]};
    if (i < 8){
      ea.it[it++] = {d_in[di_idx++], eg[i], bsz[i]};
      ea.it[it++] = {d_in[di_idx++], ebe[i], bsz[i]};
    }
  }
  k_expand<<<dim3(cdiv(3*N,256), 31), 256, 0, stream>>>(ea, it, dmode);
  // fused fp16 weight prep (W2,W3,W5 cvt + P/Q)
  k_prep<<<112, 256, 0, stream>>>(eW[2], eW[3], eW[5], eW[4], W2h, W3h, W5h, Pmh, Qmh);

  // CSR build: 2-phase counting sort (+ fused BN1 moments in phase A)
  const int nfb = cdiv(E, 4096);
  k_chist<<<nfb, 256, 0, stream>>>(ei, E, N, dmode, KK, cbc);
  k_cscan<<<1, 256, 0, stream>>>(cbc, cof, cursorC);
  k_fillA<<<nfb, 256, 0, stream>>>(ei, E, N, dmode, KK, epos, cursorC, tmp, mom);
  k_fillB<<<NBK, 512, 0, stream>>>(tmp, cof, N, E, KK, deg, offs, es);
  k_bn1<<<1, 64, 0, stream>>>(mom, (float)E, eW[1], eb[1], eg[1], ebe[1], ss1);
  k_ab<<<cdiv(N,256), 256, 0, stream>>>(epos, N, eW[1], eb[1], ss1, atb, btb);

  // conv1: m2 stats -> fused (m2 recompute, bn2relu, m3, stats, raw agg)
  k_m2stats<<<cdiv(E,128), 256, 0, stream>>>(es, atb, btb, E, W2h, eb[2], repl);
  k_finalize<<<1, 128, 0, stream>>>(repl, 64, (float)E, eg[2], ebe[2], ss2);
  k_conv1f<<<cdiv(E,128), 256, 0, stream>>>(atb, btb, es, E, ss2,
                                            W2h, eb[2], W3h, eb[3], repl, tmaxA, tminA);
  k_finalize<<<1, 128, 0, stream>>>(repl, 64, (float)E, eg[3], ebe[3], ss3);
  k_applybn<<<cdiv(N*64,256), 256, 0, stream>>>(tmaxA, tminA, ss3, (long)N*64, x1b);

  // conv2 decomposed: node GEMM (p into x2b, q into uqb) + CSR gather pass (full BN4 stats)
  k_pq<<<cdiv(N,64), 64, 0, stream>>>(x1b, N, Pmh, Qmh, eb[4], zeros64, x2b, uqb);
  k_edge2<<<cdiv(N, 4*NPW), 256, 0, stream>>>(offs, es, uqb, x2b, N, tmaxF, tminF, repl);
  k_finalize<<<1, 128, 0, stream>>>(repl, 64, (float)E, eg[4], ebe[4], ss4);
  k_applybn2<<<cdiv(N*64,256), 256, 0, stream>>>(x2b, tmaxF, tminF, deg, ss4, (long)N*64);

  // lin5 (MFMA, fused BN5 stats with correct channel offsets) + pool
  k_lin5m<<<cdiv(N,64), 64, 0, stream>>>(x1b, x2b, N, W5h, eb[5], y5b, repl);
  k_finalize<<<1, 128, 0, stream>>>(repl, 128, (float)N, eg[5], ebe[5], ss5);
  k_pool<<<cdiv(N,128), 256, 0, stream>>>(y5b, batch, N, dmode, ss5, pooled);

  // head (multi-block, BN+relu folded into consuming GEMMs)
  k_linH6<<<32, 256, 0, stream>>>(pooled, eW[6], eb[6], Y6);
  k_bnH<<<1, 128, 0, stream>>>(Y6, 128, eg[6], ebe[6], ssH);
  k_linHR<<<32, 256, 0, stream>>>(Y6, ssH, eW[7], eb[7], 128, Y7);
  k_bnH<<<1, 128, 0, stream>>>(Y7, 128, eg[7], ebe[7], ssH);
  k_linHR<<<10, 256, 0, stream>>>(Y7, ssH, eW[8], eb[8], 40, Zl);
  k_logsm<<<1, 64, 0, stream>>>(Zl, out_f);
}

// Round 17
// 615.250 us; speedup vs baseline: 1.0442x; 1.0442x over previous
//
#include <hip/hip_runtime.h>
#include <hip/hip_bf16.h>
#include <hip/hip_fp16.h>
#include <math.h>

#define EPS_BN 1e-5f
#define NBK 256

// Wire formats: float inputs bf16 (runtime-detected), ints int32/int64 (detected), OUTPUT FP32.
// r17: conv2 affine decomposition. r18: BN1 moments. r19: z1 tables. r21: weight prepack.
// r23: degS eliminated algebraically. r25: fp16 activations/weights. r26: counting-sort CSR.
// r27: transposed m3 dump + vectorized seg_walk. r28: multi-block head (632).
// r30: +XCD swizzle, 64-thr MFMA kernels -> 616us (BEST).
// r31/r32: 256-thr conv1f variants improved per-dispatch time (124->118us) but end-to-end
//      regressed (632/642) -- deltas are inside the +-15us harness noise band and the
//      launch-structure changes perturb inter-kernel scheduling.
// r33: verbatim restore of the measured-best r30 configuration.

typedef float f32x4_t  __attribute__((ext_vector_type(4)));
typedef _Float16 half8_t __attribute__((ext_vector_type(8)));
typedef _Float16 half2_t __attribute__((ext_vector_type(2)));

// ---------- helpers ----------
static __device__ __forceinline__ float bf2f(unsigned short b){
  return __uint_as_float(((unsigned)b) << 16);
}
// fp16 scalar/packed helpers
static __device__ __forceinline__ float h2f(unsigned short u){
  _Float16 h;
  __builtin_memcpy(&h, &u, 2);
  return (float)h;
}
static __device__ __forceinline__ unsigned short f2h(float f){
  _Float16 h = (_Float16)f;
  unsigned short u;
  __builtin_memcpy(&u, &h, 2);
  return u;
}
static __device__ __forceinline__ unsigned pkh2(float a, float b){
  half2_t t = { (_Float16)a, (_Float16)b };
  unsigned u;
  __builtin_memcpy(&u, &t, 4);
  return u;
}
static inline int cdiv(int a, int b){ return (a + b - 1) / b; }
static __device__ __forceinline__ int clampi(int v, int lo, int hi){
  return v < lo ? lo : (v > hi ? hi : v);
}
static __device__ __forceinline__ int ld_idx(const void* p, long e, int m64){
  return m64 ? (int)((const long long*)p)[e] : ((const int*)p)[e];
}
// order-preserving float<->uint
static __device__ __forceinline__ unsigned ordf(float f){
  unsigned b = __float_as_uint(f);
  return (b & 0x80000000u) ? ~b : (b | 0x80000000u);
}
static __device__ __forceinline__ float iordf(unsigned u){
  unsigned b = (u & 0x80000000u) ? (u & 0x7FFFFFFFu) : ~u;
  return __uint_as_float(b);
}
// bijective XCD-aware blockIdx swizzle (m204 form): each XCD gets a contiguous chunk
static __device__ __forceinline__ int xcd_swz(int orig, int nwg){
  int xcd = orig & 7;
  int base = orig >> 3;
  int q = nwg >> 3, r = nwg & 7;
  int start = (xcd < r) ? xcd*(q+1) : r*(q+1) + (xcd - r)*q;
  return start + base;
}

// ---------- sentinel ----------
__global__ void k_sentinel(float* out, int n){
  int i = blockIdx.x*256 + threadIdx.x;
  if (i < n) out[i] = -12288.0f;
}

// ---------- runtime dtype detection ----------
__global__ void k_detect(const void* ei, const void* pos, int* dmode){
  __shared__ int nz, ff;
  if (threadIdx.x == 0){ nz = 0; ff = 0; }
  __syncthreads();
  const int* w32 = (const int*)ei;
  if (w32[1 + 2*threadIdx.x] != 0) nz = 1;
  const unsigned short* ph = (const unsigned short*)pos;
  int bad = 0;
  for (int i = threadIdx.x; i < 8192; i += 256)
    if (((ph[i] >> 7) & 0xFF) == 0xFF) bad = 1;
  if (bad) ff = 1;
  __syncthreads();
  if (threadIdx.x == 0){ dmode[0] = nz ? 0 : 1; dmode[1] = ff; }
}

// ---------- expand float inputs -> fp32 scratch ----------
struct ExpItem { const void* s; float* d; int n; };
struct ExpArgs { ExpItem it[31]; };
__global__ void k_expand(ExpArgs a, int cnt, const int* dmode){
  int i = blockIdx.y;
  if (i >= cnt) return;
  int m32 = dmode[1];
  int t = blockIdx.x*256 + threadIdx.x;
  if (t < a.it[i].n){
    a.it[i].d[t] = m32 ? ((const float*)a.it[i].s)[t]
                       : bf2f(((const unsigned short*)a.it[i].s)[t]);
  }
}

// ---------- fused weight prep: W2/W3/W5 -> fp16, W4 -> P/Q fp16 ----------
__global__ void k_prep(const float* __restrict__ W2, const float* __restrict__ W3,
                       const float* __restrict__ W5, const float* __restrict__ W4,
                       unsigned short* __restrict__ W2h, unsigned short* __restrict__ W3h,
                       unsigned short* __restrict__ W5h,
                       unsigned short* __restrict__ P, unsigned short* __restrict__ Q){
  int i = blockIdx.x*256 + threadIdx.x;
  if (i < 4096) W2h[i] = f2h(W2[i]);
  else if (i < 8192) W3h[i-4096] = f2h(W3[i-4096]);
  else if (i < 24576) W5h[i-8192] = f2h(W5[i-8192]);
  else if (i < 28672){
    int j = i - 24576;
    int c = j >> 6, k = j & 63;
    float b = W4[c*128 + 64 + k];
    P[j] = f2h(W4[c*128 + k] - b);
    Q[j] = f2h(b);
  }
}

// ---------- CSR build: 2-phase counting sort ----------
// phase 0: coarse histogram (256 buckets of KK nodes) via LDS, 256 global atomics/block
__global__ void k_chist(const void* __restrict__ ei, int E, int N, const int* dmode,
                        int KK, int* __restrict__ cbc){
  __shared__ int lh[NBK];
  int tid = threadIdx.x;
  lh[tid] = 0;
  __syncthreads();
  int m64 = dmode[0];
  long base = (long)blockIdx.x*4096;
  for (int k = 0; k < 16; k++){
    long e = base + k*256 + tid;
    if (e < E){
      int nd = clampi(ld_idx(ei, (long)E + e, m64), 0, N-1);
      atomicAdd(&lh[nd/KK], 1);
    }
  }
  __syncthreads();
  if (lh[tid]) atomicAdd(&cbc[tid], lh[tid]);
}

// phase 0b: 256-entry scan -> coarse offsets cof[0..256] + phase-A cursors
__global__ void k_cscan(const int* __restrict__ cbc, int* __restrict__ cof,
                        int* __restrict__ cursorC){
  __shared__ int s[NBK];
  int t = threadIdx.x;
  int d = cbc[t];
  s[t] = d;
  __syncthreads();
  for (int off = 1; off < NBK; off <<= 1){
    int x = (t >= off) ? s[t - off] : 0;
    __syncthreads();
    s[t] += x;
    __syncthreads();
  }
  cof[t + 1] = s[t];
  cursorC[t] = s[t] - d;
  if (t == 0) cof[0] = 0;
}

// phase A: bin edges into coarse buckets. Per-block: LDS count -> reserve contiguous run
// per bucket (1 global atomic) -> stream edges into runs (dense ~128B writes).
// Fused: all 27 BN1 edge moments.
__global__ void k_fillA(const void* __restrict__ ei, int E, int N, const int* dmode,
                        int KK, const float* __restrict__ pos,
                        int* __restrict__ cursorC, int2* __restrict__ tmp,
                        float* __restrict__ mom){
  __shared__ int lh[NBK];
  __shared__ int rb[NBK];
  int tid = threadIdx.x;
  lh[tid] = 0;
  __syncthreads();
  int m64 = dmode[0];
  long base = (long)blockIdx.x*4096;
  for (int k = 0; k < 16; k++){
    long e = base + k*256 + tid;
    if (e < E){
      int nd = clampi(ld_idx(ei, (long)E + e, m64), 0, N-1);
      atomicAdd(&lh[nd/KK], 1);
    }
  }
  __syncthreads();
  int c = lh[tid];
  rb[tid] = c ? atomicAdd(&cursorC[tid], c) : 0;
  lh[tid] = 0;
  __syncthreads();
  float v[27];
  #pragma unroll
  for (int j = 0; j < 27; j++) v[j] = 0.f;
  for (int k = 0; k < 16; k++){
    long e = base + k*256 + tid;
    if (e < E){
      int sv = clampi(ld_idx(ei, e, m64), 0, N-1);
      int nd = clampi(ld_idx(ei, (long)E + e, m64), 0, N-1);
      int b = nd/KK;
      int p = rb[b] + atomicAdd(&lh[b], 1);
      tmp[p] = make_int2(nd, sv);
      float xd0=pos[nd*3+0], xd1=pos[nd*3+1], xd2=pos[nd*3+2];
      float xs0=pos[sv*3+0], xs1=pos[sv*3+1], xs2=pos[sv*3+2];
      v[0]+=xd0; v[1]+=xd1; v[2]+=xd2;
      v[3]+=xs0; v[4]+=xs1; v[5]+=xs2;
      v[6]+=xd0*xd0; v[7]+=xd0*xd1; v[8]+=xd0*xd2; v[9]+=xd1*xd1; v[10]+=xd1*xd2; v[11]+=xd2*xd2;
      v[12]+=xs0*xs0; v[13]+=xs0*xs1; v[14]+=xs0*xs2; v[15]+=xs1*xs1; v[16]+=xs1*xs2; v[17]+=xs2*xs2;
      v[18]+=xd0*xs0; v[19]+=xd0*xs1; v[20]+=xd0*xs2;
      v[21]+=xd1*xs0; v[22]+=xd1*xs1; v[23]+=xd1*xs2;
      v[24]+=xd2*xs0; v[25]+=xd2*xs1; v[26]+=xd2*xs2;
    }
  }
  #pragma unroll
  for (int m = 1; m < 64; m <<= 1){
    #pragma unroll
    for (int j = 0; j < 27; j++) v[j] += __shfl_xor(v[j], m, 64);
  }
  int lane = tid & 63;
  int wflat = (blockIdx.x*256 + tid) >> 6;
  if (lane == 0){
    float* mr = &mom[(size_t)(wflat & 63)*32];
    #pragma unroll
    for (int j = 0; j < 27; j++) atomicAdd(&mr[j], v[j]);
  }
}

// phase B: one block per coarse bucket. Local hist -> deg (dense), scan -> offs (dense),
// redistribute bucket edges to exact CSR positions (block-owned range, low write-amp).
__global__ void __launch_bounds__(512, 1)
k_fillB(const int2* __restrict__ tmp, const int* __restrict__ cof, int N, int E, int KK,
        int* __restrict__ deg, int* __restrict__ offs, int2* __restrict__ es){
  __shared__ int lh[512];
  __shared__ int lc[512];
  int tid = threadIdx.x, b = blockIdx.x;
  int nd0 = b*KK;
  int nd1 = nd0 + KK; if (nd1 > N) nd1 = N;
  int nn = nd1 - nd0; if (nn < 0) nn = 0;
  int gbase = cof[b], gend = cof[b+1];
  int cnt = gend - gbase;
  lh[tid] = 0;
  __syncthreads();
  for (int t = tid; t < cnt; t += 512)
    atomicAdd(&lh[tmp[gbase + t].x - nd0], 1);
  __syncthreads();
  int d = lh[tid];
  for (int off = 1; off < 512; off <<= 1){
    int x = (tid >= off) ? lh[tid - off] : 0;
    __syncthreads();
    lh[tid] += x;
    __syncthreads();
  }
  int excl = lh[tid] - d;
  if (tid < nn){
    deg[nd0 + tid] = d;
    offs[nd0 + tid] = gbase + excl;
  }
  lc[tid] = excl;
  if (b == gridDim.x - 1 && tid == 0) offs[N] = E;
  __syncthreads();
  for (int t = tid; t < cnt; t += 512){
    int2 e2 = tmp[gbase + t];
    int lpos = atomicAdd(&lc[e2.x - nd0], 1);
    es[gbase + lpos] = e2;
  }
}

// ---------- BN1 finalize from moments ----------
__global__ void k_bn1(const float* __restrict__ mom, float Ef,
                      const float* __restrict__ W1, const float* __restrict__ b1,
                      const float* __restrict__ g, const float* __restrict__ be,
                      float* __restrict__ ss){
  __shared__ float sm[27];
  int t = threadIdx.x;
  if (t < 27){
    float s = 0.f;
    for (int r = 0; r < 64; r++) s += mom[(size_t)r*32 + t];
    sm[t] = s;
  }
  __syncthreads();
  if (t < 64){
    float P0 = W1[t*6+0]-W1[t*6+3], P1 = W1[t*6+1]-W1[t*6+4], P2 = W1[t*6+2]-W1[t*6+5];
    float Q0 = W1[t*6+3], Q1 = W1[t*6+4], Q2 = W1[t*6+5];
    float b = b1[t];
    float vD0=sm[0],vD1=sm[1],vD2=sm[2], vS0=sm[3],vS1=sm[4],vS2=sm[5];
    float PvD = P0*vD0 + P1*vD1 + P2*vD2;
    float QvS = Q0*vS0 + Q1*vS1 + Q2*vS2;
    float sum = PvD + QvS + Ef*b;
    float PMDP = P0*(sm[6]*P0 + sm[7]*P1 + sm[8]*P2)
               + P1*(sm[7]*P0 + sm[9]*P1 + sm[10]*P2)
               + P2*(sm[8]*P0 + sm[10]*P1 + sm[11]*P2);
    float QMSQ = Q0*(sm[12]*Q0 + sm[13]*Q1 + sm[14]*Q2)
               + Q1*(sm[13]*Q0 + sm[15]*Q1 + sm[16]*Q2)
               + Q2*(sm[14]*Q0 + sm[16]*Q1 + sm[17]*Q2);
    float PGQ = P0*(sm[18]*Q0 + sm[19]*Q1 + sm[20]*Q2)
              + P1*(sm[21]*Q0 + sm[22]*Q1 + sm[23]*Q2)
              + P2*(sm[24]*Q0 + sm[25]*Q1 + sm[26]*Q2);
    float sumsq = PMDP + 2.f*b*PvD + Ef*b*b + QMSQ + 2.f*(PGQ + b*QvS);
    float mean = sum / Ef;
    float var  = fmaxf(sumsq / Ef - mean*mean, 0.f);
    float inv  = rsqrtf(var + EPS_BN);
    float sc   = g[t] * inv;
    ss[t]      = sc;
    ss[64 + t] = be[t] - mean*sc;
  }
}

// ---------- z1 tables (fp16): a' = sc1.(P.x+b1)+sh1, b = sc1.(Q.x) ----------
__global__ void k_ab(const float* __restrict__ pos, int N,
                     const float* __restrict__ W1, const float* __restrict__ b1,
                     const float* __restrict__ ss1,
                     unsigned short* __restrict__ at, unsigned short* __restrict__ bt){
  int n = blockIdx.x*256 + threadIdx.x;
  if (n >= N) return;
  float x0 = pos[n*3+0], x1 = pos[n*3+1], x2 = pos[n*3+2];
  unsigned short* ar = at + (size_t)n*64;
  unsigned short* br = bt + (size_t)n*64;
  #pragma unroll
  for (int c2 = 0; c2 < 64; c2 += 2){
    float av[2], bv[2];
    #pragma unroll
    for (int u = 0; u < 2; u++){
      int c = c2 + u;
      float q0 = W1[c*6+3], q1 = W1[c*6+4], q2 = W1[c*6+5];
      float p0 = W1[c*6+0]-q0, p1 = W1[c*6+1]-q1, p2 = W1[c*6+2]-q2;
      float sc = ss1[c], sh = ss1[64+c];
      float pa = fmaf(p0,x0, fmaf(p1,x1, fmaf(p2,x2, b1[c])));
      float qb = fmaf(q0,x0, fmaf(q1,x1, q2*x2));
      av[u] = fmaf(pa, sc, sh);
      bv[u] = qb * sc;
    }
    *(unsigned*)&ar[c2] = pkh2(av[0], av[1]);
    *(unsigned*)&br[c2] = pkh2(bv[0], bv[1]);
  }
}

// ---------- finalize BN (generic, from repl) ----------
__global__ void k_finalize(float* __restrict__ repl, int C, float count,
                           const float* __restrict__ g, const float* __restrict__ be,
                           float* __restrict__ ss){
  int c = threadIdx.x;
  if (c < C){
    float s = 0.f, q = 0.f;
    for (int r = 0; r < 64; r++){
      s += repl[r*256 + c];       repl[r*256 + c] = 0.f;
      q += repl[r*256 + 128 + c]; repl[r*256 + 128 + c] = 0.f;
    }
    float mean = s / count;
    float var  = fmaxf(q / count - mean*mean, 0.f);
    float inv  = rsqrtf(var + EPS_BN);
    float sc   = g[c] * inv;
    ss[c]     = sc;
    ss[C + c] = be[c] - mean*sc;
  }
}

// ---------- MFMA building blocks (fp16, NT-generic) ----------
// A layout (m120): lane holds A[m=lane&15][k=(lane>>4)*8+j]
// C/D layout (m89/m91, dtype-independent): col=lane&15, row=(lane>>4)*4+reg
template<int NT, int KT>
static __device__ __forceinline__ void loadBh2(const unsigned short* __restrict__ Wp, int c15, int q,
                                               half8_t bf[NT][KT]){
  #pragma unroll
  for (int nt = 0; nt < NT; nt++){
    int c = nt*16 + c15;
    #pragma unroll
    for (int kt = 0; kt < KT; kt++)
      bf[nt][kt] = *(const half8_t*)(Wp + (size_t)c*(KT*32) + kt*32 + q*8);
  }
}
template<int NT, int KT, int ST>
static __device__ __forceinline__ void do_mfma2(const unsigned short* Aw, half8_t bf[NT][KT],
                                                const float* __restrict__ bias, int c15, int q,
                                                f32x4_t acc[4][NT]){
  #pragma unroll
  for (int mt = 0; mt < 4; mt++)
    #pragma unroll
    for (int nt = 0; nt < NT; nt++){
      float bv = bias[nt*16 + c15];
      acc[mt][nt] = (f32x4_t){bv, bv, bv, bv};
    }
  #pragma unroll
  for (int mt = 0; mt < 4; mt++){
    #pragma unroll
    for (int kt = 0; kt < KT; kt++){
      half8_t af = *(const half8_t*)&Aw[(mt*16 + c15)*ST + kt*32 + q*8];
      #pragma unroll
      for (int nt = 0; nt < NT; nt++)
        acc[mt][nt] = __builtin_amdgcn_mfma_f32_16x16x32_f16(af, bf[nt][kt], acc[mt][nt], 0, 0, 0);
    }
  }
}
template<int NT>
static __device__ __forceinline__ void stats_acc2(f32x4_t acc[4][NT], long tb, int E,
                                                  int lane, int q, int r_idx, int choff,
                                                  float* __restrict__ repl){
  #pragma unroll
  for (int nt = 0; nt < NT; nt++){
    float s = 0.f, qq = 0.f;
    #pragma unroll
    for (int mt = 0; mt < 4; mt++){
      #pragma unroll
      for (int r = 0; r < 4; r++){
        long eidx = tb + mt*16 + q*4 + r;
        float v = (eidx < E) ? acc[mt][nt][r] : 0.f;
        s += v; qq += v*v;
      }
    }
    s += __shfl_xor(s, 16, 64); qq += __shfl_xor(qq, 16, 64);
    s += __shfl_xor(s, 32, 64); qq += __shfl_xor(qq, 32, 64);
    if (lane < 16){
      atomicAdd(&repl[r_idx*256 + choff + nt*16 + lane], s);
      atomicAdd(&repl[r_idx*256 + 128 + choff + nt*16 + lane], qq);
    }
  }
}
template<int NT, int ST>
static __device__ __forceinline__ void dumpC2(f32x4_t acc[4][NT], unsigned short* Cw,
                                              int colbase, int c15, int q){
  #pragma unroll
  for (int mt = 0; mt < 4; mt++)
    #pragma unroll
    for (int nt = 0; nt < NT; nt++){
      int col = colbase + nt*16 + c15;
      #pragma unroll
      for (int r = 0; r < 4; r += 2){
        unsigned p = pkh2(acc[mt][nt][r], acc[mt][nt][r+1]);
        int row = mt*16 + q*4 + r;
        Cw[row*ST + col]        = (unsigned short)p;
        Cw[(row + 1)*ST + col]  = (unsigned short)(p >> 16);
      }
    }
}
// transposed dump for m3: CT[ch][edge], stride 68 ushort (136 B). Row-pairs -> one u32.
static __device__ __forceinline__ void dumpC2T(f32x4_t acc[4][2], unsigned short* CT,
                                               int colbase, int c15, int q){
  #pragma unroll
  for (int mt = 0; mt < 4; mt++)
    #pragma unroll
    for (int nt = 0; nt < 2; nt++){
      int col = colbase + nt*16 + c15;
      #pragma unroll
      for (int r = 0; r < 4; r += 2){
        unsigned p = pkh2(acc[mt][nt][r], acc[mt][nt][r+1]);
        int row = mt*16 + q*4 + r;
        *(unsigned*)((char*)CT + col*136 + row*2) = p;
      }
    }
}
// segmented raw min/max over transposed tile; 128 threads: ch = tid&63, k-half = tid>>6.
// Vectorized: 8x ds_read_b64 values (contiguous per channel) + 8x broadcast int4 nds.
static __device__ __forceinline__ void seg_walk3(const unsigned short* CT, const int* nds,
                                                 long tb, int E, int tid,
                                                 unsigned* __restrict__ tmax,
                                                 unsigned* __restrict__ tmin){
  int lane = tid & 63, par = tid >> 6;
  long rem = (long)E - tb;
  int limit = rem >= 64 ? 64 : (rem > 0 ? (int)rem : 0);
  int k0 = par*32;
  int cnt = limit - k0; if (cnt > 32) cnt = 32;
  if (cnt <= 0) return;
  const char* base = (const char*)CT + lane*136 + k0*2;
  uint2 dv[8];
  #pragma unroll
  for (int j = 0; j < 8; j++) dv[j] = *(const uint2*)(base + j*8);
  int nd[32];
  #pragma unroll
  for (int j = 0; j < 8; j++) *(int4*)&nd[j*4] = *(const int4*)&nds[k0 + j*4];
  int cur = nd[0];
  float mx = -3.4e38f, mn = 3.4e38f;
  #pragma unroll
  for (int k = 0; k < 32; k++){
    unsigned w = (k & 2) ? dv[k>>2].y : dv[k>>2].x;
    unsigned short hv = (k & 1) ? (unsigned short)(w >> 16) : (unsigned short)(w & 0xffffu);
    float v = h2f(hv);
    bool act = (k < cnt);
    int ndk = act ? nd[k] : cur;
    if (ndk != cur){
      atomicMax(&tmax[(size_t)cur*64 + lane], ordf(mx));
      atomicMin(&tmin[(size_t)cur*64 + lane], ordf(mn));
      cur = ndk; mx = v; mn = v;
    } else if (act){
      mx = fmaxf(mx, v); mn = fminf(mn, v);
    }
  }
  atomicMax(&tmax[(size_t)cur*64 + lane], ordf(mx));
  atomicMin(&tmin[(size_t)cur*64 + lane], ordf(mn));
}
// packed fp16 add + relu (v_pk_add_f16 + v_pk_max_f16) via native _Float16 vectors
static __device__ __forceinline__ unsigned rladd2h(unsigned a, unsigned b){
  half2_t ha, hb;
  __builtin_memcpy(&ha, &a, 4);
  __builtin_memcpy(&hb, &b, 4);
  half2_t s = ha + hb;
  half2_t z = { (_Float16)0, (_Float16)0 };
  half2_t r = __builtin_elementwise_max(s, z);
  unsigned u;
  __builtin_memcpy(&u, &r, 4);
  return u;
}
// stage half (32 channels) of z1 = relu(a'[dst] + b[src]) into A row
static __device__ __forceinline__ void stage_z1t_half(const unsigned short* __restrict__ at,
                                                      const unsigned short* __restrict__ bt,
                                                      int di, int si, int h, unsigned short* Ar){
  const uint4* a4 = (const uint4*)(at + (size_t)di*64 + h*32);
  const uint4* b4 = (const uint4*)(bt + (size_t)si*64 + h*32);
  #pragma unroll
  for (int k = 0; k < 4; k++){
    uint4 av = a4[k], bv = b4[k], o;
    o.x = rladd2h(av.x, bv.x); o.y = rladd2h(av.y, bv.y);
    o.z = rladd2h(av.z, bv.z); o.w = rladd2h(av.w, bv.w);
    *(uint4*)&Ar[k*8] = o;
  }
}

// ---------- m2 stats only (CSR order, 2-wave split-N, XCD-swizzled) ----------
__global__ void __launch_bounds__(128, 1)
k_m2stats(const int2* __restrict__ es,
          const unsigned short* __restrict__ at, const unsigned short* __restrict__ bt,
          int E,
          const unsigned short* __restrict__ W2h, const float* __restrict__ b2,
          float* __restrict__ repl){
  __shared__ unsigned short A[64][72];
  int tid = threadIdx.x;
  int lane = tid & 63, wv = tid >> 6;
  int swz = xcd_swz(blockIdx.x, gridDim.x);
  long tb = (long)swz*64;
  long e = tb + lane;
  unsigned short* Ar = &A[lane][wv*32];
  if (e < E){
    int2 e2 = es[e];
    stage_z1t_half(at, bt, e2.x, e2.y, wv, Ar);
  } else {
    #pragma unroll
    for (int k = 0; k < 4; k++) *(uint4*)&Ar[k*8] = make_uint4(0u,0u,0u,0u);
  }
  __syncthreads();
  int c15 = lane & 15, q = lane >> 4;
  half8_t bf[2][2];
  loadBh2<2,2>(W2h + (size_t)(wv*32)*64, c15, q, bf);
  f32x4_t acc[4][2];
  do_mfma2<2,2,72>(&A[0][0], bf, b2 + wv*32, c15, q, acc);
  stats_acc2<2>(acc, tb, E, lane, q, swz & 63, wv*32, repl);
}

// ---------- conv1 fused (2-wave split-N, XCD-swizzled): z1t -> m2 -> bn2relu -> m3 -> stats + agg ----------
__global__ void __launch_bounds__(128, 1)
k_conv1f(const unsigned short* __restrict__ at, const unsigned short* __restrict__ bt,
         const int2* __restrict__ es, int E,
         const float* __restrict__ ss2,
         const unsigned short* __restrict__ W2h, const float* __restrict__ b2,
         const unsigned short* __restrict__ W3h, const float* __restrict__ b3,
         float* __restrict__ repl, unsigned* __restrict__ tmax, unsigned* __restrict__ tmin){
  __shared__ unsigned short A[64][72];
  __shared__ int nds[64];
  int tid = threadIdx.x;
  int lane = tid & 63, wv = tid >> 6;
  int swz = xcd_swz(blockIdx.x, gridDim.x);
  long tb = (long)swz*64;
  long t = tb + lane;
  unsigned short* Ar = &A[lane][wv*32];
  if (t < E){
    int2 e2 = es[t];
    if (wv == 0) nds[lane] = e2.x;
    stage_z1t_half(at, bt, e2.x, e2.y, wv, Ar);
  } else {
    if (wv == 0) nds[lane] = 0;
    #pragma unroll
    for (int k = 0; k < 4; k++) *(uint4*)&Ar[k*8] = make_uint4(0u,0u,0u,0u);
  }
  __syncthreads();
  int c15 = lane & 15, q = lane >> 4;
  unsigned short* Aw = &A[0][0];
  f32x4_t acc[4][2];
  {
    half8_t bf[2][2];
    loadBh2<2,2>(W2h + (size_t)(wv*32)*64, c15, q, bf);
    do_mfma2<2,2,72>(Aw, bf, b2 + wv*32, c15, q, acc);
  }
  #pragma unroll
  for (int nt = 0; nt < 2; nt++){
    int ch = wv*32 + nt*16 + c15;
    float sc = ss2[ch], sh = ss2[64 + ch];
    #pragma unroll
    for (int mt = 0; mt < 4; mt++)
      #pragma unroll
      for (int r = 0; r < 4; r++)
        acc[mt][nt][r] = fmaxf(fmaf(acc[mt][nt][r], sc, sh), 0.f);
  }
  __syncthreads();
  dumpC2<2,72>(acc, Aw, wv*32, c15, q);
  __syncthreads();
  {
    half8_t bf[2][2];
    loadBh2<2,2>(W3h + (size_t)(wv*32)*64, c15, q, bf);
    do_mfma2<2,2,72>(Aw, bf, b3 + wv*32, c15, q, acc);
  }
  stats_acc2<2>(acc, tb, E, lane, q, swz & 63, wv*32, repl);
  __syncthreads();
  // m3 C transposed into the (now dead) A buffer: CT[ch][edge], stride 68
  dumpC2T(acc, Aw, wv*32, c15, q);
  __syncthreads();
  seg_walk3(Aw, nds, tb, E, tid, tmax, tmin);
}

// ---------- conv2 decomposed: per-node p = P@x+b4, q = Q@x (no stats; BN4 from k_edge2) ----------
__global__ void __launch_bounds__(64, 1)
k_pq(const unsigned short* __restrict__ x1, int N,
     const unsigned short* __restrict__ Pmh, const unsigned short* __restrict__ Qmh,
     const float* __restrict__ b4, const float* __restrict__ zeros64,
     unsigned short* __restrict__ up, unsigned short* __restrict__ uq){
  __shared__ unsigned short A[64][72];
  __shared__ unsigned short Cb[64][72];
  int lane = threadIdx.x;
  long nb0 = (long)blockIdx.x*64;
  long n = nb0 + lane;
  unsigned short* Ar = &A[lane][0];
  if (n < N){
    const uint4* a4 = (const uint4*)(x1 + (size_t)n*64);
    #pragma unroll
    for (int k = 0; k < 8; k++) *(uint4*)&Ar[k*8] = a4[k];
  } else {
    #pragma unroll
    for (int k = 0; k < 8; k++) *(uint4*)&Ar[k*8] = make_uint4(0u,0u,0u,0u);
  }
  __syncthreads();
  int c15 = lane & 15, q = lane >> 4;
  unsigned short* Aw = &A[0][0];
  unsigned short* Cw = &Cb[0][0];
  for (int h = 0; h < 2; h++){
    const unsigned short* Wp = h ? Qmh : Pmh;
    const float* bp = h ? zeros64 : b4;
    unsigned short* out = h ? uq : up;
    half8_t bf[4][2];
    loadBh2<4,2>(Wp, c15, q, bf);
    f32x4_t acc[4][4];
    do_mfma2<4,2,72>(Aw, bf, bp, c15, q, acc);
    dumpC2<4,72>(acc, Cw, 0, c15, q);
    __syncthreads();
    int rl = lane >> 3, ch8 = lane & 7;
    #pragma unroll
    for (int pass = 0; pass < 8; pass++){
      int row = pass*8 + rl;
      long nn = nb0 + row;
      if (nn < N)
        *(uint4*)(out + (size_t)nn*64 + ch8*8) = *(const uint4*)&Cw[row*72 + ch8*8];
    }
    __syncthreads();
  }
}

// ---------- conv2 edge pass: gather max/min of q + FULL BN4 stats from segments ----------
#define NPW 8
__global__ void k_edge2(const int* __restrict__ offs, const int2* __restrict__ es,
                        const unsigned short* __restrict__ uq, const unsigned short* __restrict__ up,
                        int N, float* __restrict__ tmaxF, float* __restrict__ tminF,
                        float* __restrict__ repl){
  int wv = threadIdx.x >> 6, lane = threadIdx.x & 63;
  int w_id = blockIdx.x*4 + wv;
  int n0 = w_id * NPW;
  int nend = n0 + NPW; if (nend > N) nend = N;
  float s_acc = 0.f, ss_acc = 0.f;
  for (int n = n0; n < nend; n++){
    int e0 = offs[n], e1 = offs[n+1];
    if (e1 <= e0) continue;
    float mx = -3.4e38f, mn = 3.4e38f, qs = 0.f, qsq = 0.f;
    int t = e0;
    for (; t + 4 <= e1; t += 4){
      int s0 = es[t].y, s1 = es[t+1].y, s2 = es[t+2].y, s3 = es[t+3].y;
      float v0 = h2f(uq[(size_t)s0*64 + lane]);
      float v1 = h2f(uq[(size_t)s1*64 + lane]);
      float v2 = h2f(uq[(size_t)s2*64 + lane]);
      float v3 = h2f(uq[(size_t)s3*64 + lane]);
      mx = fmaxf(mx, fmaxf(fmaxf(v0, v1), fmaxf(v2, v3)));
      mn = fminf(mn, fminf(fminf(v0, v1), fminf(v2, v3)));
      qs += (v0 + v1) + (v2 + v3);
      qsq += v0*v0 + v1*v1 + v2*v2 + v3*v3;
    }
    for (; t < e1; t++){
      int s0 = es[t].y;
      float v0 = h2f(uq[(size_t)s0*64 + lane]);
      mx = fmaxf(mx, v0); mn = fminf(mn, v0); qs += v0; qsq += v0*v0;
    }
    float pv = h2f(up[(size_t)n*64 + lane]);
    float deg = (float)(e1 - e0);
    // Sum_e (p+q) = deg*p + qs ; Sum_e (p+q)^2 = deg*p^2 + 2p*qs + qsq
    s_acc  += fmaf(deg, pv, qs);
    ss_acc += fmaf(deg*pv, pv, fmaf(2.f*pv, qs, qsq));
    tmaxF[(size_t)n*64 + lane] = mx;
    tminF[(size_t)n*64 + lane] = mn;
  }
  int r_idx = w_id & 63;
  atomicAdd(&repl[r_idx*256 + lane], s_acc);
  atomicAdd(&repl[r_idx*256 + 128 + lane], ss_acc);
}

// ---------- conv2 post: x2 = relu(sc*(p + qext) + sh), 0 for empty segments ----------
__global__ void k_applybn2(unsigned short* __restrict__ x2 /* in: up, out: x2 (in-place) */,
                           const float* __restrict__ tmaxF, const float* __restrict__ tminF,
                           const int* __restrict__ degD, const float* __restrict__ ss,
                           long total){
  long i = (long)blockIdx.x*256 + threadIdx.x;
  if (i >= total) return;
  int c = (int)(i & 63);
  long n = i >> 6;
  float out = 0.f;
  if (degD[n] > 0){
    float sc = ss[c], sh = ss[64 + c];
    float v = h2f(x2[i]) + ((sc >= 0.f) ? tmaxF[i] : tminF[i]);
    out = fmaxf(fmaf(v, sc, sh), 0.f);
  }
  x2[i] = f2h(out);
}

// ---------- apply BN post-aggregation (conv1) ----------
__global__ void k_applybn(const unsigned* __restrict__ tmax, const unsigned* __restrict__ tmin,
                          const float* __restrict__ ss, long total,
                          unsigned short* __restrict__ xout){
  long i = (long)blockIdx.x*256 + threadIdx.x;
  if (i >= total) return;
  int c = (int)(i & 63);
  unsigned um = tmax[i];
  float out = 0.f;
  if (um != 0u){
    float sc = ss[c], sh = ss[64 + c];
    float v = (sc >= 0.f) ? iordf(um) : iordf(tmin[i]);
    out = fmaxf(fmaf(v, sc, sh), 0.f);
  }
  xout[i] = f2h(out);
}

// ---------- lin5 (MFMA, single-wave WG): y5 = cat(x1,x2)@W5^T + b5, fused BN5 stats ----------
__global__ void __launch_bounds__(64, 1)
k_lin5m(const unsigned short* __restrict__ x1, const unsigned short* __restrict__ x2,
        int N, const unsigned short* __restrict__ W5h, const float* __restrict__ b5,
        unsigned short* __restrict__ y5, float* __restrict__ repl){
  __shared__ unsigned short A[64][136];
  __shared__ unsigned short Cb[64][72];
  int lane = threadIdx.x;
  long nb0 = (long)blockIdx.x*64;
  long n = nb0 + lane;
  unsigned short* Ar = &A[lane][0];
  if (n < N){
    const uint4* a4 = (const uint4*)(x1 + (size_t)n*64);
    const uint4* b4 = (const uint4*)(x2 + (size_t)n*64);
    #pragma unroll
    for (int k = 0; k < 8; k++) *(uint4*)&Ar[k*8]      = a4[k];
    #pragma unroll
    for (int k = 0; k < 8; k++) *(uint4*)&Ar[64 + k*8] = b4[k];
  } else {
    #pragma unroll
    for (int k = 0; k < 16; k++) *(uint4*)&Ar[k*8] = make_uint4(0u,0u,0u,0u);
  }
  __syncthreads();
  int c15 = lane & 15, q = lane >> 4;
  int r_idx = blockIdx.x & 63;
  unsigned short* Aw = &A[0][0];
  unsigned short* Cw = &Cb[0][0];
  for (int h = 0; h < 2; h++){
    const unsigned short* Wp = W5h + (size_t)h*64*128;
    half8_t bf[4][4];
    loadBh2<4,4>(Wp, c15, q, bf);
    f32x4_t acc[4][4];
    do_mfma2<4,4,136>(Aw, bf, b5 + h*64, c15, q, acc);
    stats_acc2<4>(acc, nb0, N, lane, q, r_idx, h*64, repl);
    dumpC2<4,72>(acc, Cw, 0, c15, q);
    __syncthreads();
    int rl = lane >> 3, ch8 = lane & 7;
    #pragma unroll
    for (int pass = 0; pass < 8; pass++){
      int row = pass*8 + rl;
      long nn = nb0 + row;
      if (nn < N)
        *(uint4*)(y5 + (size_t)nn*128 + h*64 + ch8*8) = *(const uint4*)&Cw[row*72 + ch8*8];
    }
    __syncthreads();
  }
}

// ---------- pool ----------
__global__ void k_pool(const unsigned short* __restrict__ y5, const void* __restrict__ batch, int N,
                       const int* dmode, const float* __restrict__ ss5, unsigned int* __restrict__ pooled){
  int m64 = dmode[0];
  int c = threadIdx.x & 127;
  int par = threadIdx.x >> 7;
  int n0 = blockIdx.x*128;
  int n1 = min(n0 + 128, N);
  float sc = ss5[c], sh = ss5[128 + c];
  int curb = -1; float curm = 0.f;
  for (int n = n0 + par; n < n1; n += 2){
    int b = clampi(ld_idx(batch, (long)n, m64), 0, 63);
    float v = fmaf(h2f(y5[(size_t)n*128 + c]), sc, sh);
    if (b != curb){
      if (curb >= 0) atomicMax(&pooled[curb*128 + c], __float_as_uint(fmaxf(curm, 0.f)));
      curb = b; curm = v;
    } else {
      curm = fmaxf(curm, v);
    }
  }
  if (curb >= 0) atomicMax(&pooled[curb*128 + c], __float_as_uint(fmaxf(curm, 0.f)));
}

// ---------- head (multi-block, unfused) ----------
// lin6: Y = pooled(float bits) @ W6^T + b6
__global__ void k_linH6(const unsigned int* __restrict__ X, const float* __restrict__ W,
                        const float* __restrict__ b, float* __restrict__ Y){
  int cell = blockIdx.x*256 + threadIdx.x;
  if (cell >= 8192) return;
  int r = cell >> 7, c = cell & 127;
  const unsigned int* xr = X + r*128;
  const float* wr = W + c*128;
  float a = b[c];
  for (int j = 0; j < 128; j++) a = fmaf(__uint_as_float(xr[j]), wr[j], a);
  Y[cell] = a;
}

// BN stats over 64 rows -> ss
__global__ void k_bnH(const float* __restrict__ Y, int CO,
                      const float* __restrict__ g, const float* __restrict__ be,
                      float* __restrict__ ss){
  int c = threadIdx.x;
  if (c >= CO) return;
  float s = 0.f;
  for (int r = 0; r < 64; r++) s += Y[r*CO + c];
  float mean = s * (1.f/64.f);
  float q = 0.f;
  for (int r = 0; r < 64; r++){ float d = Y[r*CO + c] - mean; q += d*d; }
  float var = fmaxf(q * (1.f/64.f), 0.f);
  float inv = rsqrtf(var + EPS_BN);
  float sc = g[c] * inv;
  ss[c] = sc;
  ss[CO + c] = be[c] - mean*sc;
}

// lin with BN+relu folded on the input: Z[r][c] = b[c] + sum_j relu(Y[r][j]*sc[j]+sh[j])*W[c][j]
__global__ void k_linHR(const float* __restrict__ Y, const float* __restrict__ ssH,
                        const float* __restrict__ W, const float* __restrict__ b,
                        int CO, float* __restrict__ Z){
  int cell = blockIdx.x*256 + threadIdx.x;
  if (cell >= 64*CO) return;
  int r = cell / CO, c = cell - r*CO;
  const float* xr = Y + r*128;
  const float* wr = W + c*128;
  float a = b[c];
  for (int j = 0; j < 128; j++){
    float x = fmaxf(fmaf(xr[j], ssH[j], ssH[128 + j]), 0.f);
    a = fmaf(x, wr[j], a);
  }
  Z[cell] = a;
}

__global__ void k_logsm(const float* __restrict__ Z, float* __restrict__ out){
  int r = threadIdx.x;   // 64 threads
  const float* zr = Z + r*40;
  float m = zr[0];
  for (int c = 1; c < 40; c++) m = fmaxf(m, zr[c]);
  float s = 0.f;
  for (int c = 0; c < 40; c++) s += expf(zr[c] - m);
  float ls = logf(s);
  for (int c = 0; c < 40; c++) out[r*40 + c] = zr[c] - m - ls;
}

// ---------- launch ----------
extern "C" void kernel_launch(void* const* d_in, const int* in_sizes, int n_in,
                              void* d_out, int out_size, void* d_ws, size_t ws_size,
                              hipStream_t stream) {
  const void* pos   = d_in[0];
  const void* ei    = d_in[1];
  const void* batch = d_in[2];
  (void)n_in;

  const int N = in_sizes[0] / 3;
  const int E = in_sizes[1] / 2;
  const int KK = cdiv(N, NBK);   // nodes per coarse bucket

  // ---- workspace layout ----
  auto al = [](size_t x){ return (x + 255) & ~(size_t)255; };
  char* w = (char*)d_ws;
  size_t o = 0;
  float* repl = (float*)(w + o);                 o += (size_t)64*256*4;
  unsigned int* pooled = (unsigned int*)(w + o); o += (size_t)64*128*4;
  float* zeros64 = (float*)(w + o);              o += 256;
  float* mom = (float*)(w + o);                  o += (size_t)64*32*4;
  int* cbc = (int*)(w + o);                      o += 1024;
  size_t zero_bytes = o;
  int* cof = (int*)(w + o);                      o += 2048;
  int* cursorC = (int*)(w + o);                  o += 1024;
  int* deg = (int*)(w + o);                      o += al((size_t)4*N);
  unsigned* tmaxA = (unsigned*)(w + o);          o += (size_t)64*N*4;
  unsigned* tminA = (unsigned*)(w + o);          o += (size_t)64*N*4;
  // conv2 float min/max reuse conv1's buffers (consumed by k_applybn before k_edge2)
  float* tmaxF = (float*)tmaxA;
  float* tminF = (float*)tminA;
  int* dmode = (int*)(w + o);                    o += 256;
  int* offs = (int*)(w + o);                     o += al((size_t)4*(N + 1));
  int2* tmp = (int2*)(w + o);                    o += al((size_t)8*E);
  int2* es = (int2*)(w + o);                     o += al((size_t)8*E);
  float* ss1 = (float*)(w + o);                  o += 1024;
  float* ss2 = (float*)(w + o);                  o += 1024;
  float* ss3 = (float*)(w + o);                  o += 1024;
  float* ss4 = (float*)(w + o);                  o += 1024;
  float* ss5 = (float*)(w + o);                  o += 1024;
  float* ssH = (float*)(w + o);                  o += 1024;
  float* Y6 = (float*)(w + o);                   o += (size_t)8192*4;
  float* Y7 = (float*)(w + o);                   o += (size_t)8192*4;
  float* Zl = (float*)(w + o);                   o += al((size_t)2560*4);
  unsigned short* W2h = (unsigned short*)(w + o); o += 8192;
  unsigned short* W3h = (unsigned short*)(w + o); o += 8192;
  unsigned short* W5h = (unsigned short*)(w + o); o += 32768;
  unsigned short* Pmh = (unsigned short*)(w + o); o += 8192;
  unsigned short* Qmh = (unsigned short*)(w + o); o += 8192;
  // fp32 expansion region
  float* expBase = (float*)(w + o);
  float* ep = expBase;
  float* epos = ep; ep += (size_t)3*N;
  float* eW[9], *eb[9], *eg[9], *ebe[9];
  const int wsz[9] = {0, 64*6, 64*64, 64*64, 64*128, 128*128, 128*128, 128*128, 40*128};
  const int bsz[9] = {0, 64, 64, 64, 64, 128, 128, 128, 40};
  for (int i = 1; i <= 8; i++){
    eW[i] = ep; ep += wsz[i];
    eb[i] = ep; ep += bsz[i];
    if (i < 8){ eg[i] = ep; ep += bsz[i]; ebe[i] = ep; ep += bsz[i]; }
  }
  long expCount = (long)(ep - expBase);
  o += al((size_t)expCount * 4);
  unsigned short* x1b = (unsigned short*)(w + o); o += al((size_t)2*64*N);
  unsigned short* x2b = (unsigned short*)(w + o); o += al((size_t)2*64*N);  // also holds p (up)
  unsigned short* uqb = (unsigned short*)(w + o); o += al((size_t)2*64*N);
  unsigned short* atb = (unsigned short*)(w + o); o += al((size_t)2*64*N);  // z1 table a'
  unsigned short* btb = (unsigned short*)(w + o); o += al((size_t)2*64*N);  // z1 table b
  unsigned short* y5b = (unsigned short*)(w + o); o += al((size_t)2*128*N);

  float* out_f = (float*)d_out;
  if (ws_size < o){
    k_sentinel<<<cdiv(out_size,256), 256, 0, stream>>>(out_f, out_size);
    return;
  }

  hipMemsetAsync(w, 0, zero_bytes, stream);
  hipMemsetAsync(tmaxA, 0x00, (size_t)64*N*4, stream);
  hipMemsetAsync(tminA, 0xFF, (size_t)64*N*4, stream);
  k_detect<<<1, 256, 0, stream>>>(ei, pos, dmode);

  // expand all float inputs -> fp32
  ExpArgs ea;
  int it = 0;
  ea.it[it++] = {pos, epos, 3*N};
  int di_idx = 3;
  for (int i = 1; i <= 8; i++){
    ea.it[it++] = {d_in[di_idx++], eW[i], wsz[i]};
    ea.it[it++] = {d_in[di_idx++], eb[i], bsz[i]};
    if (i < 8){
      ea.it[it++] = {d_in[di_idx++], eg[i], bsz[i]};
      ea.it[it++] = {d_in[di_idx++], ebe[i], bsz[i]};
    }
  }
  k_expand<<<dim3(cdiv(3*N,256), 31), 256, 0, stream>>>(ea, it, dmode);
  // fused fp16 weight prep (W2,W3,W5 cvt + P/Q)
  k_prep<<<112, 256, 0, stream>>>(eW[2], eW[3], eW[5], eW[4], W2h, W3h, W5h, Pmh, Qmh);

  // CSR build: 2-phase counting sort (+ fused BN1 moments in phase A)
  const int nfb = cdiv(E, 4096);
  k_chist<<<nfb, 256, 0, stream>>>(ei, E, N, dmode, KK, cbc);
  k_cscan<<<1, 256, 0, stream>>>(cbc, cof, cursorC);
  k_fillA<<<nfb, 256, 0, stream>>>(ei, E, N, dmode, KK, epos, cursorC, tmp, mom);
  k_fillB<<<NBK, 512, 0, stream>>>(tmp, cof, N, E, KK, deg, offs, es);
  k_bn1<<<1, 64, 0, stream>>>(mom, (float)E, eW[1], eb[1], eg[1], ebe[1], ss1);
  k_ab<<<cdiv(N,256), 256, 0, stream>>>(epos, N, eW[1], eb[1], ss1, atb, btb);

  // conv1: m2 stats -> fused (m2 recompute, bn2relu, m3, stats, raw agg)
  k_m2stats<<<cdiv(E,64), 128, 0, stream>>>(es, atb, btb, E, W2h, eb[2], repl);
  k_finalize<<<1, 128, 0, stream>>>(repl, 64, (float)E, eg[2], ebe[2], ss2);
  k_conv1f<<<cdiv(E,64), 128, 0, stream>>>(atb, btb, es, E, ss2,
                                           W2h, eb[2], W3h, eb[3], repl, tmaxA, tminA);
  k_finalize<<<1, 128, 0, stream>>>(repl, 64, (float)E, eg[3], ebe[3], ss3);
  k_applybn<<<cdiv(N*64,256), 256, 0, stream>>>(tmaxA, tminA, ss3, (long)N*64, x1b);

  // conv2 decomposed: node GEMM (p into x2b, q into uqb) + CSR gather pass (full BN4 stats)
  k_pq<<<cdiv(N,64), 64, 0, stream>>>(x1b, N, Pmh, Qmh, eb[4], zeros64, x2b, uqb);
  k_edge2<<<cdiv(N, 4*NPW), 256, 0, stream>>>(offs, es, uqb, x2b, N, tmaxF, tminF, repl);
  k_finalize<<<1, 128, 0, stream>>>(repl, 64, (float)E, eg[4], ebe[4], ss4);
  k_applybn2<<<cdiv(N*64,256), 256, 0, stream>>>(x2b, tmaxF, tminF, deg, ss4, (long)N*64);

  // lin5 (MFMA, fused BN5 stats with correct channel offsets) + pool
  k_lin5m<<<cdiv(N,64), 64, 0, stream>>>(x1b, x2b, N, W5h, eb[5], y5b, repl);
  k_finalize<<<1, 128, 0, stream>>>(repl, 128, (float)N, eg[5], ebe[5], ss5);
  k_pool<<<cdiv(N,128), 256, 0, stream>>>(y5b, batch, N, dmode, ss5, pooled);

  // head (multi-block, BN+relu folded into consuming GEMMs)
  k_linH6<<<32, 256, 0, stream>>>(pooled, eW[6], eb[6], Y6);
  k_bnH<<<1, 128, 0, stream>>>(Y6, 128, eg[6], ebe[6], ssH);
  k_linHR<<<32, 256, 0, stream>>>(Y6, ssH, eW[7], eb[7], 128, Y7);
  k_bnH<<<1, 128, 0, stream>>>(Y7, 128, eg[7], ebe[7], ssH);
  k_linHR<<<10, 256, 0, stream>>>(Y7, ssH, eW[8], eb[8], 40, Zl);
  k_logsm<<<1, 64, 0, stream>>>(Zl, out_f);
}